// Round 2
// 3034.057 us; speedup vs baseline: 2.5653x; 2.5653x over previous
//
#include <hip/hip_runtime.h>
#include <hip/hip_bf16.h>
#include <type_traits>

// Model_50981261804324 — round 8 (MFMA rewrite), resubmitted after broker timeout.
// Theory: all big GEMMs were fp32 VALU (MfmaUtil=0, VALUBusy=74%). Replace with
// error-compensated split-bf16 MFMA (hi/lo planes, 3-term: ah*wh+al*wh+ah*wl;
// 2-term when A already bf16). fp32-faithful to ~2^-16 => absmax unchanged.
// Weights transposed+split per call into [N][Kpad] bf16 planes; activations
// split by producer kernels (ln/pe/flash) — hbuf eliminated.
// mgemm: 128x128 tile, 4 waves, BK=64, XOR-swizzled LDS (T2), reg-prefetch (T3-min),
// XCD-bijective block swizzle. WS need ~214MB — checked up front.

using bf16 = __hip_bfloat16;
using s16x8 = __attribute__((ext_vector_type(8))) short;
using f32x4 = __attribute__((ext_vector_type(4))) float;

#define BB   16
#define LL   512
#define DM   768
#define DFF  3072
#define DLLM 1024
#define GDFF 512
#define NH   12
#define DH   64

__device__ __forceinline__ float braw2f(unsigned short r) {
  union { unsigned u; float f; } c; c.u = ((unsigned)r) << 16; return c.f;
}
__device__ __forceinline__ unsigned short f2b_rn(float x) {
  union { float f; unsigned u; } c; c.f = x;
  unsigned r = c.u + 0x7fffu + ((c.u >> 16) & 1u);
  return (unsigned short)(r >> 16);
}
// split fp32 into hi (truncated bf16, exact) + lo (bf16 of residual)
__device__ __forceinline__ void split2(float v, unsigned short& h, unsigned short& l) {
  union { float f; unsigned u; } c; c.f = v;
  c.u &= 0xffff0000u;
  h = (unsigned short)(c.u >> 16);
  l = f2b_rn(v - c.f);
}
__device__ __forceinline__ float gelu_tanh(float x) {
  float x3 = x * x * x;
  return 0.5f * x * (1.f + tanhf(0.7978845608028654f * (x + 0.044715f * x3)));
}
// LDS byte-offset swizzle: row stride 128B (64 bf16); spreads 8 rows over 8 granules
__device__ __forceinline__ int swz(int r, int k) {
  return ((r << 7) + (k << 1)) ^ ((r & 7) << 4);
}

// ---------------------------------------------------------------------------
// dkp = DKP_embeddings[16,1024] @ W_gate[1024,512]  (tiny)
__global__ __launch_bounds__(256) void dkp_kernel(const float* __restrict__ E,
                                                  const float* __restrict__ Wg,
                                                  float* __restrict__ dkp) {
  int idx = blockIdx.x * 256 + threadIdx.x;      // 8192
  int b = idx >> 9, n = idx & 511;
  const float* e = E + b * DLLM;
  float acc = 0.f;
  for (int k = 0; k < DLLM; ++k) acc += e[k] * Wg[k * GDFF + n];
  dkp[idx] = acc;
}

__global__ __launch_bounds__(256) void gate_kernel(const float* __restrict__ dkp,
                                                   const float* __restrict__ Wg,
                                                   const float* __restrict__ bg,
                                                   const int* __restrict__ cm,
                                                   float* __restrict__ gout) {
  int idx = blockIdx.x * 256 + threadIdx.x;      // 16*3072
  int b = idx / DFF, n = idx % DFF;
  const float* d = dkp + b * GDFF;
  float acc = 0.f;
  for (int k = 0; k < GDFF; ++k) acc += d[k] * Wg[k * DFF + n];
  acc += bg[n];
  float g = 1.f / (1.f + expf(-acc));
  float km = (n < 1280) ? (float)cm[b * 20 + (n >> 6)] : 1.f;
  gout[idx] = g * km;
}

// ---------------------------------------------------------------------------
// Weight prep: W [K][N] fp32 -> Wh,Wl [N][Kpad] bf16 planes (transposed, padded).
// blockIdx.z batches stacked layers.
__global__ __launch_bounds__(256) void wprep_kernel(const float* __restrict__ W,
                                                    unsigned short* __restrict__ Wh,
                                                    unsigned short* __restrict__ Wl,
                                                    int K, int N, int Kpad) {
  __shared__ float tile[32][33];
  const int z = blockIdx.z;
  W  += (size_t)z * K * N;
  Wh += (size_t)z * N * Kpad;
  Wl += (size_t)z * N * Kpad;
  const int kb = blockIdx.x * 32, nb = blockIdx.y * 32;
  const int tx = threadIdx.x & 31, ty = threadIdx.x >> 5;  // 32 x 8
#pragma unroll
  for (int i = 0; i < 32; i += 8) {
    int k = kb + ty + i;
    tile[ty + i][tx] = (k < K) ? W[(size_t)k * N + nb + tx] : 0.f;
  }
  __syncthreads();
#pragma unroll
  for (int i = 0; i < 32; i += 8) {
    int n = nb + ty + i, k = kb + tx;
    float v = tile[tx][ty + i];
    unsigned short h, l;
    split2(v, h, l);
    size_t o = (size_t)n * Kpad + k;
    Wh[o] = h; Wl[o] = l;
  }
}

// ccd [8192][900] * mask[row] -> AspH/AspL [8192][960] bf16 planes (zero-padded K)
__global__ __launch_bounds__(256) void asplit_kernel(const float* __restrict__ A,
                                                     const float* __restrict__ rs,
                                                     unsigned short* __restrict__ H,
                                                     unsigned short* __restrict__ L) {
  int idx = blockIdx.x * 256 + threadIdx.x;      // 8192*960
  int r = idx / 960, k = idx - r * 960;
  float v = (k < 900) ? A[(size_t)r * 900 + k] * rs[r] : 0.f;
  unsigned short h, l;
  split2(v, h, l);
  H[idx] = h; L[idx] = l;
}

// ---------------------------------------------------------------------------
// Split-bf16 MFMA GEMM: C[8192,N] = epi(A[8192,Kpad] @ W^T-planes + bias)
// A as bf16 planes Ah(+Al if ALO); W as transposed planes Wh,Wl [N][Kpad].
// acc = Ah*Wh + Ah*Wl (+ Al*Wh). MODE 0: +bias; 1: gelu*gate; 2: +bias+res.
template <int MODE, bool ALO, typename CT>
__global__ __launch_bounds__(256) void mgemm_kernel(
    const unsigned short* __restrict__ Ah, const unsigned short* __restrict__ Al,
    const unsigned short* __restrict__ Wh, const unsigned short* __restrict__ Wl,
    const float* __restrict__ bias, const float* __restrict__ gate,
    const float* __restrict__ res, CT* __restrict__ C, int N, int Kpad) {
  __shared__ unsigned short Ah_s[128 * 64];
  __shared__ unsigned short Al_s[ALO ? 128 * 64 : 8];
  __shared__ unsigned short Wh_s[128 * 64];
  __shared__ unsigned short Wl_s[128 * 64];

  const int t = threadIdx.x;
  // XCD-bijective swizzle (all grids have nwg % 8 == 0)
  const int nbx = gridDim.x;
  const int nwg = nbx * gridDim.y;
  int bid = blockIdx.y * nbx + blockIdx.x;
  bid = (bid & 7) * (nwg >> 3) + (bid >> 3);
  const int n0 = (bid % nbx) * 128;
  const int m0 = (bid / nbx) * 128;

  const int lane = t & 63;
  const int wav = t >> 6;
  const int wr = (wav >> 1) * 64;
  const int wc = (wav & 1) * 64;
  const int lr = lane & 15;
  const int lk = (lane >> 4) * 8;
  const int sr = t >> 3;           // staging row 0..31 (+32*it)
  const int sk = (t & 7) * 8;      // staging k 0..56

  f32x4 acc[4][4];
#pragma unroll
  for (int i = 0; i < 4; ++i)
#pragma unroll
    for (int j = 0; j < 4; ++j) acc[i][j] = (f32x4){0.f, 0.f, 0.f, 0.f};

  s16x8 va[4], val[4], vw[4], vwl[4];
  auto load_tile = [&](int k0) {
#pragma unroll
    for (int it = 0; it < 4; ++it) {
      const int r = sr + it * 32;
      const size_t gw = (size_t)(n0 + r) * Kpad + (k0 + sk);
      const size_t ga = (size_t)(m0 + r) * Kpad + (k0 + sk);
      vw[it]  = *(const s16x8*)(Wh + gw);
      vwl[it] = *(const s16x8*)(Wl + gw);
      va[it]  = *(const s16x8*)(Ah + ga);
      if constexpr (ALO) val[it] = *(const s16x8*)(Al + ga);
    }
  };
  load_tile(0);

  for (int k0 = 0; k0 < Kpad; k0 += 64) {
    __syncthreads();   // previous compute's LDS reads done
#pragma unroll
    for (int it = 0; it < 4; ++it) {
      const int so = swz(sr + it * 32, sk);
      *(s16x8*)((char*)Wh_s + so) = vw[it];
      *(s16x8*)((char*)Wl_s + so) = vwl[it];
      *(s16x8*)((char*)Ah_s + so) = va[it];
      if constexpr (ALO) *(s16x8*)((char*)Al_s + so) = val[it];
    }
    __syncthreads();
    if (k0 + 64 < Kpad) load_tile(k0 + 64);  // prefetch hides under MFMA

#pragma unroll
    for (int kk = 0; kk < 64; kk += 32) {
      s16x8 fa[4], fal[4], fwh[4], fwl[4];
#pragma unroll
      for (int f = 0; f < 4; ++f) {
        fwh[f] = *(const s16x8*)((const char*)Wh_s + swz(wc + f * 16 + lr, kk + lk));
        fwl[f] = *(const s16x8*)((const char*)Wl_s + swz(wc + f * 16 + lr, kk + lk));
        fa[f]  = *(const s16x8*)((const char*)Ah_s + swz(wr + f * 16 + lr, kk + lk));
        if constexpr (ALO)
          fal[f] = *(const s16x8*)((const char*)Al_s + swz(wr + f * 16 + lr, kk + lk));
      }
#pragma unroll
      for (int i = 0; i < 4; ++i)
#pragma unroll
        for (int j = 0; j < 4; ++j) {
          acc[i][j] = __builtin_amdgcn_mfma_f32_16x16x32_bf16(fa[i], fwh[j], acc[i][j], 0, 0, 0);
          acc[i][j] = __builtin_amdgcn_mfma_f32_16x16x32_bf16(fa[i], fwl[j], acc[i][j], 0, 0, 0);
          if constexpr (ALO)
            acc[i][j] = __builtin_amdgcn_mfma_f32_16x16x32_bf16(fal[i], fwh[j], acc[i][j], 0, 0, 0);
        }
    }
  }

  // epilogue: C/D layout col=lane&15, row=(lane>>4)*4+e
  const int cr = (lane >> 4) * 4;
  const int gb = (m0 >> 9) * DFF;   // 128-row tile lies in one batch
#pragma unroll
  for (int i = 0; i < 4; ++i) {
#pragma unroll
    for (int j = 0; j < 4; ++j) {
      const int gc = n0 + wc + j * 16 + lr;
      const float bb = bias[gc];
#pragma unroll
      for (int e = 0; e < 4; ++e) {
        const int gr = m0 + wr + i * 16 + cr + e;
        float v = acc[i][j][e] + bb;
        if constexpr (MODE == 1) v = gelu_tanh(v) * gate[gb + gc];
        if constexpr (MODE == 2) v += res[(size_t)gr * N + gc];
        if constexpr (std::is_same<CT, float>::value) C[(size_t)gr * N + gc] = v;
        else C[(size_t)gr * N + gc] = f2b_rn(v);
      }
    }
  }
}

// ---------------------------------------------------------------------------
// LayerNorm; optionally writes fp32 and always writes split bf16 planes.
__global__ __launch_bounds__(256) void ln_kernel(const float* __restrict__ src,
                                                 float* __restrict__ dstF,
                                                 unsigned short* __restrict__ dH,
                                                 unsigned short* __restrict__ dL) {
  __shared__ float rs_[256], rq_[256];
  const int row = blockIdx.x, t = threadIdx.x;
  const float* p = src + (size_t)row * DM;
  float x0 = p[t], x1 = p[t + 256], x2 = p[t + 512];
  rs_[t] = x0 + x1 + x2;
  rq_[t] = x0 * x0 + x1 * x1 + x2 * x2;
  __syncthreads();
  for (int off = 128; off; off >>= 1) {
    if (t < off) { rs_[t] += rs_[t + off]; rq_[t] += rq_[t + off]; }
    __syncthreads();
  }
  float mean = rs_[0] * (1.f / 768.f);
  float var = rq_[0] * (1.f / 768.f) - mean * mean;
  float inv = rsqrtf(var + 1e-5f);
  float y0 = (x0 - mean) * inv, y1 = (x1 - mean) * inv, y2 = (x2 - mean) * inv;
  if (dstF) {
    float* q = dstF + (size_t)row * DM;
    q[t] = y0; q[t + 256] = y1; q[t + 512] = y2;
  }
  const size_t base = (size_t)row * DM;
  unsigned short h, lo;
  split2(y0, h, lo); dH[base + t] = h;       dL[base + t] = lo;
  split2(y1, h, lo); dH[base + t + 256] = h; dL[base + t + 256] = lo;
  split2(y2, h, lo); dH[base + t + 512] = h; dL[base + t + 512] = lo;
}

// out += sinusoidal PE; also writes split planes (feeds layer-0 Q/K/V GEMMs)
__global__ __launch_bounds__(256) void pe_kernel(float* __restrict__ out,
                                                 unsigned short* __restrict__ dH,
                                                 unsigned short* __restrict__ dL) {
  int idx = blockIdx.x * 256 + threadIdx.x;
  int c = idx % DM;
  int pl = (idx / DM) & (LL - 1);
  float freq = expf((float)(c & ~1) * (-9.210340371976184f / 768.f));
  float ang = (float)pl * freq;
  float o = out[idx] + ((c & 1) ? cosf(ang) : sinf(ang));
  out[idx] = o;
  unsigned short h, lo;
  split2(o, h, lo);
  dH[idx] = h; dL[idx] = lo;
}

// ---------------------------------------------------------------------------
// Flash attention (unchanged math); epilogue writes split bf16 planes.
__global__ __launch_bounds__(256) void flash_kernel(const unsigned short* __restrict__ q,
                                                    const unsigned short* __restrict__ k,
                                                    const unsigned short* __restrict__ v,
                                                    const float* __restrict__ mask,
                                                    unsigned short* __restrict__ OH,
                                                    unsigned short* __restrict__ OL) {
  __shared__ float Qs[64][65];
  __shared__ unsigned short Ks[64][66], Vs[64][66];
  __shared__ float Ps[64][65];
  __shared__ float msk[64];
  const int qt = blockIdx.x, hh = blockIdx.y, b = blockIdx.z;
  const int t = threadIdx.x;
  const int ty = t >> 2, tx = t & 3;
  const int c0 = tx * 16;
  const size_t qoff = ((size_t)(b * LL + qt * 64 + ty)) * DM + hh * DH + c0;
#pragma unroll
  for (int i = 0; i < 16; ++i) Qs[ty][c0 + i] = braw2f(q[qoff + i]) * 0.125f;

  float m = -1e30f, l = 0.f;
  float O[16];
#pragma unroll
  for (int i = 0; i < 16; ++i) O[i] = 0.f;

  for (int kt = 0; kt < 8; ++kt) {
    __syncthreads();
    const size_t koff = ((size_t)(b * LL + kt * 64 + ty)) * DM + hh * DH + c0;
#pragma unroll
    for (int i = 0; i < 16; ++i) {
      Ks[ty][c0 + i] = k[koff + i];
      Vs[ty][c0 + i] = v[koff + i];
    }
    if (t < 64) msk[t] = mask[b * LL + kt * 64 + t];
    __syncthreads();

    float s[16];
#pragma unroll
    for (int j = 0; j < 16; ++j) {
      int kc = c0 + j;
      float a = 0.f;
#pragma unroll 8
      for (int d = 0; d < 64; ++d) a = fmaf(Qs[ty][d], braw2f(Ks[kc][d]), a);
      s[j] = (msk[kc] == 0.f) ? -1e9f : a;
    }
    float rmax = s[0];
#pragma unroll
    for (int j = 1; j < 16; ++j) rmax = fmaxf(rmax, s[j]);
    rmax = fmaxf(rmax, __shfl_xor(rmax, 1));
    rmax = fmaxf(rmax, __shfl_xor(rmax, 2));
    float nm = fmaxf(m, rmax);
    float alpha = expf(m - nm);
    float ps = 0.f;
#pragma unroll
    for (int j = 0; j < 16; ++j) {
      float pv = expf(s[j] - nm);
      Ps[ty][c0 + j] = pv;
      ps += pv;
    }
    ps += __shfl_xor(ps, 1);
    ps += __shfl_xor(ps, 2);
    l = l * alpha + ps;
    m = nm;
#pragma unroll
    for (int i = 0; i < 16; ++i) O[i] *= alpha;
    __syncthreads();
#pragma unroll 4
    for (int kk = 0; kk < 64; ++kk) {
      float pv = Ps[ty][kk];
#pragma unroll
      for (int i = 0; i < 16; ++i) O[i] = fmaf(pv, braw2f(Vs[kk][c0 + i]), O[i]);
    }
  }
  float inv = 1.f / l;
#pragma unroll
  for (int i = 0; i < 16; i += 2) {
    unsigned short h0, l0, h1, l1;
    split2(O[i] * inv, h0, l0);
    split2(O[i + 1] * inv, h1, l1);
    *(unsigned int*)(OH + qoff + i) = (unsigned)h0 | ((unsigned)h1 << 16);
    *(unsigned int*)(OL + qoff + i) = (unsigned)l0 | ((unsigned)l1 << 16);
  }
}

// ---------------------------------------------------------------------------
// Final: per-batch gather last valid row, LN, head matmul. Writes FP32 out.
__global__ __launch_bounds__(256) void final_kernel(const float* __restrict__ out,
                                                    const float* __restrict__ mask,
                                                    const float* __restrict__ Wh,
                                                    const float* __restrict__ bh,
                                                    float* __restrict__ dout) {
  __shared__ float rs[256], rq[256];
  const int b = blockIdx.x, t = threadIdx.x;
  rs[t] = mask[b * LL + t] + mask[b * LL + 256 + t];
  __syncthreads();
  for (int off = 128; off; off >>= 1) {
    if (t < off) rs[t] += rs[t + off];
    __syncthreads();
  }
  int idx = (int)(rs[0] + 0.5f) - 1;
  if (idx < 0) idx = 0;
  __syncthreads();

  const float* row = out + ((size_t)b * LL + idx) * DM;
  float x0 = row[t], x1 = row[t + 256], x2 = row[t + 512];
  rs[t] = x0 + x1 + x2;
  rq[t] = x0 * x0 + x1 * x1 + x2 * x2;
  __syncthreads();
  for (int off = 128; off; off >>= 1) {
    if (t < off) { rs[t] += rs[t + off]; rq[t] += rq[t + off]; }
    __syncthreads();
  }
  float mean = rs[0] * (1.f / 768.f);
  float var = rq[0] * (1.f / 768.f) - mean * mean;
  float inv = rsqrtf(var + 1e-5f);
  float y0 = (x0 - mean) * inv, y1 = (x1 - mean) * inv, y2 = (x2 - mean) * inv;
  dout[16 + b * DM + t] = y0;
  dout[16 + b * DM + 256 + t] = y1;
  dout[16 + b * DM + 512 + t] = y2;
  __syncthreads();
  rs[t] = y0 * Wh[t] + y1 * Wh[t + 256] + y2 * Wh[t + 512];
  __syncthreads();
  for (int off = 128; off; off >>= 1) {
    if (t < off) rs[t] += rs[t + off];
    __syncthreads();
  }
  if (t == 0) dout[b] = rs[0] + bh[0];
}

// ---------------------------------------------------------------------------
extern "C" void kernel_launch(void* const* d_in, const int* in_sizes, int n_in,
                              void* d_out, int out_size, void* d_ws, size_t ws_size,
                              hipStream_t stream) {
  const float* ccd    = (const float*)d_in[0];
  const float* mask   = (const float*)d_in[1];
  const float* dkpE   = (const float*)d_in[2];
  const int*   cmask  = (const int*)d_in[3];
  const float* W_gate = (const float*)d_in[4];
  const float* We1 = (const float*)d_in[5];
  const float* be1 = (const float*)d_in[6];
  const float* Weg = (const float*)d_in[7];
  const float* beg = (const float*)d_in[8];
  const float* We2 = (const float*)d_in[9];
  const float* be2 = (const float*)d_in[10];
  const float* Wm1 = (const float*)d_in[11];
  const float* bm1 = (const float*)d_in[12];
  const float* Wmg = (const float*)d_in[13];
  const float* bmg = (const float*)d_in[14];
  const float* Wm2 = (const float*)d_in[15];
  const float* bm2 = (const float*)d_in[16];
  const float* Wq = (const float*)d_in[17];
  const float* Wk = (const float*)d_in[18];
  const float* Wv = (const float*)d_in[19];
  const float* Wo = (const float*)d_in[20];
  const float* bq = (const float*)d_in[21];
  const float* bk = (const float*)d_in[22];
  const float* bv = (const float*)d_in[23];
  const float* bo = (const float*)d_in[24];
  const float* Wf1 = (const float*)d_in[25];
  const float* bf1 = (const float*)d_in[26];
  const float* Wfg = (const float*)d_in[27];
  const float* bfg = (const float*)d_in[28];
  const float* Wf2 = (const float*)d_in[29];
  const float* bf2 = (const float*)d_in[30];
  const float* W_head = (const float*)d_in[31];
  const float* b_head = (const float*)d_in[32];

  // ---- workspace layout (~214 MiB)
  char* base = (char*)d_ws;
  size_t used = 0;
  auto alloc = [&](size_t bytes) -> char* {
    char* r = base + used;
    used += (bytes + 255) & ~(size_t)255;
    return r;
  };
  float* dkp   = (float*)alloc((size_t)8192 * 4);
  float* gates = (float*)alloc((size_t)5 * 16 * DFF * 4);
  float* out   = (float*)alloc((size_t)8192 * DM * 4);
  unsigned short* ubuf = (unsigned short*)alloc((size_t)8192 * DFF * 2);
  unsigned short* AspH = (unsigned short*)alloc((size_t)8192 * 960 * 2);
  unsigned short* AspL = (unsigned short*)alloc((size_t)8192 * 960 * 2);
  const size_t szWe1 = (size_t)3072 * 960;
  const size_t szKN  = (size_t)3072 * 768;
  const size_t szAtt = (size_t)768 * 768;
  unsigned short* We1tH = (unsigned short*)alloc(szWe1 * 2);
  unsigned short* We1tL = (unsigned short*)alloc(szWe1 * 2);
  unsigned short* We2tH = (unsigned short*)alloc(szKN * 2);
  unsigned short* We2tL = (unsigned short*)alloc(szKN * 2);
  unsigned short* Wm1tH = (unsigned short*)alloc(2 * szKN * 2);
  unsigned short* Wm1tL = (unsigned short*)alloc(2 * szKN * 2);
  unsigned short* Wm2tH = (unsigned short*)alloc(2 * szKN * 2);
  unsigned short* Wm2tL = (unsigned short*)alloc(2 * szKN * 2);
  unsigned short* WqtH = (unsigned short*)alloc(2 * szAtt * 2);
  unsigned short* WqtL = (unsigned short*)alloc(2 * szAtt * 2);
  unsigned short* WktH = (unsigned short*)alloc(2 * szAtt * 2);
  unsigned short* WktL = (unsigned short*)alloc(2 * szAtt * 2);
  unsigned short* WvtH = (unsigned short*)alloc(2 * szAtt * 2);
  unsigned short* WvtL = (unsigned short*)alloc(2 * szAtt * 2);
  unsigned short* WotH = (unsigned short*)alloc(2 * szAtt * 2);
  unsigned short* WotL = (unsigned short*)alloc(2 * szAtt * 2);
  unsigned short* Wf1tH = (unsigned short*)alloc(2 * szKN * 2);
  unsigned short* Wf1tL = (unsigned short*)alloc(2 * szKN * 2);
  unsigned short* Wf2tH = (unsigned short*)alloc(2 * szKN * 2);
  unsigned short* Wf2tL = (unsigned short*)alloc(2 * szKN * 2);
  unsigned short* qb = ubuf;                          // aliases: disjoint lifetimes
  unsigned short* kb = ubuf + (size_t)8192 * DM;
  unsigned short* vb = ubuf + (size_t)2 * 8192 * DM;
  if (used > ws_size) return;  // diagnostic: ws too small => output unwritten

  dim3 blk(256);

  // ---- weight prep (transpose + hi/lo split)
  wprep_kernel<<<dim3(30, 96, 1), blk, 0, stream>>>(We1, We1tH, We1tL, 900, 3072, 960);
  wprep_kernel<<<dim3(96, 24, 1), blk, 0, stream>>>(We2, We2tH, We2tL, 3072, 768, 3072);
  wprep_kernel<<<dim3(24, 96, 2), blk, 0, stream>>>(Wm1, Wm1tH, Wm1tL, 768, 3072, 768);
  wprep_kernel<<<dim3(96, 24, 2), blk, 0, stream>>>(Wm2, Wm2tH, Wm2tL, 3072, 768, 3072);
  wprep_kernel<<<dim3(24, 24, 2), blk, 0, stream>>>(Wq, WqtH, WqtL, 768, 768, 768);
  wprep_kernel<<<dim3(24, 24, 2), blk, 0, stream>>>(Wk, WktH, WktL, 768, 768, 768);
  wprep_kernel<<<dim3(24, 24, 2), blk, 0, stream>>>(Wv, WvtH, WvtL, 768, 768, 768);
  wprep_kernel<<<dim3(24, 24, 2), blk, 0, stream>>>(Wo, WotH, WotL, 768, 768, 768);
  wprep_kernel<<<dim3(24, 96, 2), blk, 0, stream>>>(Wf1, Wf1tH, Wf1tL, 768, 3072, 768);
  wprep_kernel<<<dim3(96, 24, 2), blk, 0, stream>>>(Wf2, Wf2tH, Wf2tL, 3072, 768, 3072);

  asplit_kernel<<<30720, blk, 0, stream>>>(ccd, mask, AspH, AspL);

  // gates
  dkp_kernel<<<32, blk, 0, stream>>>(dkpE, W_gate, dkp);
  const float* Wgs[5] = {Weg, Wmg, Wmg + (size_t)GDFF * DFF, Wfg, Wfg + (size_t)GDFF * DFF};
  const float* bgs[5] = {beg, bmg, bmg + DFF, bfg, bfg + DFF};
  for (int g = 0; g < 5; ++g)
    gate_kernel<<<192, blk, 0, stream>>>(dkp, Wgs[g], bgs[g], cmask, gates + (size_t)g * 16 * DFF);

  // patch embed gated FFN
  mgemm_kernel<1, true, unsigned short><<<dim3(24, 64), blk, 0, stream>>>(
      AspH, AspL, We1tH, We1tL, be1, gates, nullptr, ubuf, DFF, 960);
  mgemm_kernel<0, false, float><<<dim3(6, 64), blk, 0, stream>>>(
      ubuf, nullptr, We2tH, We2tL, be2, nullptr, nullptr, out, DM, DFF);

  // intra MLP blocks: out += gated_ffn(ln(out))
  for (int i = 0; i < 2; ++i) {
    ln_kernel<<<8192, blk, 0, stream>>>(out, nullptr, AspH, AspL);
    mgemm_kernel<1, true, unsigned short><<<dim3(24, 64), blk, 0, stream>>>(
        AspH, AspL, Wm1tH + (size_t)i * szKN, Wm1tL + (size_t)i * szKN,
        bm1 + i * DFF, gates + (size_t)(1 + i) * 16 * DFF, nullptr, ubuf, DFF, DM);
    mgemm_kernel<2, false, float><<<dim3(6, 64), blk, 0, stream>>>(
        ubuf, nullptr, Wm2tH + (size_t)i * szKN, Wm2tL + (size_t)i * szKN,
        bm2 + i * DM, nullptr, out, out, DM, DFF);
  }

  pe_kernel<<<24576, blk, 0, stream>>>(out, AspH, AspL);

  // encoder layers
  for (int i = 0; i < 2; ++i) {
    size_t wof = (size_t)i * szAtt;
    mgemm_kernel<0, true, unsigned short><<<dim3(6, 64), blk, 0, stream>>>(
        AspH, AspL, WqtH + wof, WqtL + wof, bq + i * DM, nullptr, nullptr, qb, DM, DM);
    mgemm_kernel<0, true, unsigned short><<<dim3(6, 64), blk, 0, stream>>>(
        AspH, AspL, WktH + wof, WktL + wof, bk + i * DM, nullptr, nullptr, kb, DM, DM);
    mgemm_kernel<0, true, unsigned short><<<dim3(6, 64), blk, 0, stream>>>(
        AspH, AspL, WvtH + wof, WvtL + wof, bv + i * DM, nullptr, nullptr, vb, DM, DM);
    flash_kernel<<<dim3(8, 12, 16), blk, 0, stream>>>(qb, kb, vb, mask, AspH, AspL);
    mgemm_kernel<2, true, float><<<dim3(6, 64), blk, 0, stream>>>(
        AspH, AspL, WotH + wof, WotL + wof, bo + i * DM, nullptr, out, out, DM, DM);
    ln_kernel<<<8192, blk, 0, stream>>>(out, out, AspH, AspL);
    mgemm_kernel<1, true, unsigned short><<<dim3(24, 64), blk, 0, stream>>>(
        AspH, AspL, Wf1tH + (size_t)i * szKN, Wf1tL + (size_t)i * szKN,
        bf1 + i * DFF, gates + (size_t)(3 + i) * 16 * DFF, nullptr, ubuf, DFF, DM);
    mgemm_kernel<2, false, float><<<dim3(6, 64), blk, 0, stream>>>(
        ubuf, nullptr, Wf2tH + (size_t)i * szKN, Wf2tL + (size_t)i * szKN,
        bf2 + i * DM, nullptr, out, out, DM, DFF);
    ln_kernel<<<8192, blk, 0, stream>>>(out, out, AspH, AspL);
  }

  final_kernel<<<16, blk, 0, stream>>>(out, mask, W_head, b_head, (float*)d_out);
}

// Round 3
// 2207.411 us; speedup vs baseline: 3.5260x; 1.3745x over previous
//
#include <hip/hip_runtime.h>
#include <hip/hip_bf16.h>
#include <type_traits>

// Model_50981261804324 — round 9: MFMA flash attention.
// r8 post-mortem: GEMMs now MFMA (7783->3034us, absmax unchanged). Top cost is
// flash_kernel (2x528us, MfmaUtil=0, VALUBusy=70%, 4.1e7 bank conflicts).
// This round: QK^T and PV on the matrix pipe. Q/K row-major LDS, V transposed
// (Vt[d][k]) so all MFMA fragments are contiguous swizzled 16B reads (same swz
// as mgemm). Online softmax on the D-layout (col=lane&15,row=(lane>>4)*4+e):
// per-lane max over 4 col-tiles + 4 shfl_xor. P->bf16 into wave-private LDS
// rows (no barrier needed before PV; intra-wave lgkmcnt suffices). 2 barriers
// per k-tile, register prefetch of next K/V tile. __expf replaces expf.
// Predicted: flash 528 -> ~90-150us, total ~2100-2300us, absmax 0.015625.

using bf16 = __hip_bfloat16;
using s16x8 = __attribute__((ext_vector_type(8))) short;
using f32x4 = __attribute__((ext_vector_type(4))) float;

#define BB   16
#define LL   512
#define DM   768
#define DFF  3072
#define DLLM 1024
#define GDFF 512
#define NH   12
#define DH   64

__device__ __forceinline__ float braw2f(unsigned short r) {
  union { unsigned u; float f; } c; c.u = ((unsigned)r) << 16; return c.f;
}
__device__ __forceinline__ unsigned short f2b_rn(float x) {
  union { float f; unsigned u; } c; c.f = x;
  unsigned r = c.u + 0x7fffu + ((c.u >> 16) & 1u);
  return (unsigned short)(r >> 16);
}
// split fp32 into hi (truncated bf16, exact) + lo (bf16 of residual)
__device__ __forceinline__ void split2(float v, unsigned short& h, unsigned short& l) {
  union { float f; unsigned u; } c; c.f = v;
  c.u &= 0xffff0000u;
  h = (unsigned short)(c.u >> 16);
  l = f2b_rn(v - c.f);
}
__device__ __forceinline__ float gelu_tanh(float x) {
  float x3 = x * x * x;
  return 0.5f * x * (1.f + tanhf(0.7978845608028654f * (x + 0.044715f * x3)));
}
// LDS byte-offset swizzle: row stride 128B (64 bf16); spreads 8 rows over 8 granules
__device__ __forceinline__ int swz(int r, int k) {
  return ((r << 7) + (k << 1)) ^ ((r & 7) << 4);
}

// ---------------------------------------------------------------------------
// dkp = DKP_embeddings[16,1024] @ W_gate[1024,512]  (tiny)
__global__ __launch_bounds__(256) void dkp_kernel(const float* __restrict__ E,
                                                  const float* __restrict__ Wg,
                                                  float* __restrict__ dkp) {
  int idx = blockIdx.x * 256 + threadIdx.x;      // 8192
  int b = idx >> 9, n = idx & 511;
  const float* e = E + b * DLLM;
  float acc = 0.f;
  for (int k = 0; k < DLLM; ++k) acc += e[k] * Wg[k * GDFF + n];
  dkp[idx] = acc;
}

__global__ __launch_bounds__(256) void gate_kernel(const float* __restrict__ dkp,
                                                   const float* __restrict__ Wg,
                                                   const float* __restrict__ bg,
                                                   const int* __restrict__ cm,
                                                   float* __restrict__ gout) {
  int idx = blockIdx.x * 256 + threadIdx.x;      // 16*3072
  int b = idx / DFF, n = idx % DFF;
  const float* d = dkp + b * GDFF;
  float acc = 0.f;
  for (int k = 0; k < GDFF; ++k) acc += d[k] * Wg[k * DFF + n];
  acc += bg[n];
  float g = 1.f / (1.f + expf(-acc));
  float km = (n < 1280) ? (float)cm[b * 20 + (n >> 6)] : 1.f;
  gout[idx] = g * km;
}

// ---------------------------------------------------------------------------
// Weight prep: W [K][N] fp32 -> Wh,Wl [N][Kpad] bf16 planes (transposed, padded).
__global__ __launch_bounds__(256) void wprep_kernel(const float* __restrict__ W,
                                                    unsigned short* __restrict__ Wh,
                                                    unsigned short* __restrict__ Wl,
                                                    int K, int N, int Kpad) {
  __shared__ float tile[32][33];
  const int z = blockIdx.z;
  W  += (size_t)z * K * N;
  Wh += (size_t)z * N * Kpad;
  Wl += (size_t)z * N * Kpad;
  const int kb = blockIdx.x * 32, nb = blockIdx.y * 32;
  const int tx = threadIdx.x & 31, ty = threadIdx.x >> 5;  // 32 x 8
#pragma unroll
  for (int i = 0; i < 32; i += 8) {
    int k = kb + ty + i;
    tile[ty + i][tx] = (k < K) ? W[(size_t)k * N + nb + tx] : 0.f;
  }
  __syncthreads();
#pragma unroll
  for (int i = 0; i < 32; i += 8) {
    int n = nb + ty + i, k = kb + tx;
    float v = tile[tx][ty + i];
    unsigned short h, l;
    split2(v, h, l);
    size_t o = (size_t)n * Kpad + k;
    Wh[o] = h; Wl[o] = l;
  }
}

// ccd [8192][900] * mask[row] -> AspH/AspL [8192][960] bf16 planes (zero-padded K)
__global__ __launch_bounds__(256) void asplit_kernel(const float* __restrict__ A,
                                                     const float* __restrict__ rs,
                                                     unsigned short* __restrict__ H,
                                                     unsigned short* __restrict__ L) {
  int idx = blockIdx.x * 256 + threadIdx.x;      // 8192*960
  int r = idx / 960, k = idx - r * 960;
  float v = (k < 900) ? A[(size_t)r * 900 + k] * rs[r] : 0.f;
  unsigned short h, l;
  split2(v, h, l);
  H[idx] = h; L[idx] = l;
}

// ---------------------------------------------------------------------------
// Split-bf16 MFMA GEMM: C[8192,N] = epi(A[8192,Kpad] @ W^T-planes + bias)
template <int MODE, bool ALO, typename CT>
__global__ __launch_bounds__(256) void mgemm_kernel(
    const unsigned short* __restrict__ Ah, const unsigned short* __restrict__ Al,
    const unsigned short* __restrict__ Wh, const unsigned short* __restrict__ Wl,
    const float* __restrict__ bias, const float* __restrict__ gate,
    const float* __restrict__ res, CT* __restrict__ C, int N, int Kpad) {
  __shared__ unsigned short Ah_s[128 * 64];
  __shared__ unsigned short Al_s[ALO ? 128 * 64 : 8];
  __shared__ unsigned short Wh_s[128 * 64];
  __shared__ unsigned short Wl_s[128 * 64];

  const int t = threadIdx.x;
  // XCD-bijective swizzle (all grids have nwg % 8 == 0)
  const int nbx = gridDim.x;
  const int nwg = nbx * gridDim.y;
  int bid = blockIdx.y * nbx + blockIdx.x;
  bid = (bid & 7) * (nwg >> 3) + (bid >> 3);
  const int n0 = (bid % nbx) * 128;
  const int m0 = (bid / nbx) * 128;

  const int lane = t & 63;
  const int wav = t >> 6;
  const int wr = (wav >> 1) * 64;
  const int wc = (wav & 1) * 64;
  const int lr = lane & 15;
  const int lk = (lane >> 4) * 8;
  const int sr = t >> 3;           // staging row 0..31 (+32*it)
  const int sk = (t & 7) * 8;      // staging k 0..56

  f32x4 acc[4][4];
#pragma unroll
  for (int i = 0; i < 4; ++i)
#pragma unroll
    for (int j = 0; j < 4; ++j) acc[i][j] = (f32x4){0.f, 0.f, 0.f, 0.f};

  s16x8 va[4], val[4], vw[4], vwl[4];
  auto load_tile = [&](int k0) {
#pragma unroll
    for (int it = 0; it < 4; ++it) {
      const int r = sr + it * 32;
      const size_t gw = (size_t)(n0 + r) * Kpad + (k0 + sk);
      const size_t ga = (size_t)(m0 + r) * Kpad + (k0 + sk);
      vw[it]  = *(const s16x8*)(Wh + gw);
      vwl[it] = *(const s16x8*)(Wl + gw);
      va[it]  = *(const s16x8*)(Ah + ga);
      if constexpr (ALO) val[it] = *(const s16x8*)(Al + ga);
    }
  };
  load_tile(0);

  for (int k0 = 0; k0 < Kpad; k0 += 64) {
    __syncthreads();   // previous compute's LDS reads done
#pragma unroll
    for (int it = 0; it < 4; ++it) {
      const int so = swz(sr + it * 32, sk);
      *(s16x8*)((char*)Wh_s + so) = vw[it];
      *(s16x8*)((char*)Wl_s + so) = vwl[it];
      *(s16x8*)((char*)Ah_s + so) = va[it];
      if constexpr (ALO) *(s16x8*)((char*)Al_s + so) = val[it];
    }
    __syncthreads();
    if (k0 + 64 < Kpad) load_tile(k0 + 64);  // prefetch hides under MFMA

#pragma unroll
    for (int kk = 0; kk < 64; kk += 32) {
      s16x8 fa[4], fal[4], fwh[4], fwl[4];
#pragma unroll
      for (int f = 0; f < 4; ++f) {
        fwh[f] = *(const s16x8*)((const char*)Wh_s + swz(wc + f * 16 + lr, kk + lk));
        fwl[f] = *(const s16x8*)((const char*)Wl_s + swz(wc + f * 16 + lr, kk + lk));
        fa[f]  = *(const s16x8*)((const char*)Ah_s + swz(wr + f * 16 + lr, kk + lk));
        if constexpr (ALO)
          fal[f] = *(const s16x8*)((const char*)Al_s + swz(wr + f * 16 + lr, kk + lk));
      }
#pragma unroll
      for (int i = 0; i < 4; ++i)
#pragma unroll
        for (int j = 0; j < 4; ++j) {
          acc[i][j] = __builtin_amdgcn_mfma_f32_16x16x32_bf16(fa[i], fwh[j], acc[i][j], 0, 0, 0);
          acc[i][j] = __builtin_amdgcn_mfma_f32_16x16x32_bf16(fa[i], fwl[j], acc[i][j], 0, 0, 0);
          if constexpr (ALO)
            acc[i][j] = __builtin_amdgcn_mfma_f32_16x16x32_bf16(fal[i], fwh[j], acc[i][j], 0, 0, 0);
        }
    }
  }

  // epilogue: C/D layout col=lane&15, row=(lane>>4)*4+e
  const int cr = (lane >> 4) * 4;
  const int gb = (m0 >> 9) * DFF;   // 128-row tile lies in one batch
#pragma unroll
  for (int i = 0; i < 4; ++i) {
#pragma unroll
    for (int j = 0; j < 4; ++j) {
      const int gc = n0 + wc + j * 16 + lr;
      const float bb = bias[gc];
#pragma unroll
      for (int e = 0; e < 4; ++e) {
        const int gr = m0 + wr + i * 16 + cr + e;
        float v = acc[i][j][e] + bb;
        if constexpr (MODE == 1) v = gelu_tanh(v) * gate[gb + gc];
        if constexpr (MODE == 2) v += res[(size_t)gr * N + gc];
        if constexpr (std::is_same<CT, float>::value) C[(size_t)gr * N + gc] = v;
        else C[(size_t)gr * N + gc] = f2b_rn(v);
      }
    }
  }
}

// ---------------------------------------------------------------------------
// LayerNorm; optionally writes fp32 and always writes split bf16 planes.
__global__ __launch_bounds__(256) void ln_kernel(const float* __restrict__ src,
                                                 float* __restrict__ dstF,
                                                 unsigned short* __restrict__ dH,
                                                 unsigned short* __restrict__ dL) {
  __shared__ float rs_[256], rq_[256];
  const int row = blockIdx.x, t = threadIdx.x;
  const float* p = src + (size_t)row * DM;
  float x0 = p[t], x1 = p[t + 256], x2 = p[t + 512];
  rs_[t] = x0 + x1 + x2;
  rq_[t] = x0 * x0 + x1 * x1 + x2 * x2;
  __syncthreads();
  for (int off = 128; off; off >>= 1) {
    if (t < off) { rs_[t] += rs_[t + off]; rq_[t] += rq_[t + off]; }
    __syncthreads();
  }
  float mean = rs_[0] * (1.f / 768.f);
  float var = rq_[0] * (1.f / 768.f) - mean * mean;
  float inv = rsqrtf(var + 1e-5f);
  float y0 = (x0 - mean) * inv, y1 = (x1 - mean) * inv, y2 = (x2 - mean) * inv;
  if (dstF) {
    float* q = dstF + (size_t)row * DM;
    q[t] = y0; q[t + 256] = y1; q[t + 512] = y2;
  }
  const size_t base = (size_t)row * DM;
  unsigned short h, lo;
  split2(y0, h, lo); dH[base + t] = h;       dL[base + t] = lo;
  split2(y1, h, lo); dH[base + t + 256] = h; dL[base + t + 256] = lo;
  split2(y2, h, lo); dH[base + t + 512] = h; dL[base + t + 512] = lo;
}

// out += sinusoidal PE; also writes split planes (feeds layer-0 Q/K/V GEMMs)
__global__ __launch_bounds__(256) void pe_kernel(float* __restrict__ out,
                                                 unsigned short* __restrict__ dH,
                                                 unsigned short* __restrict__ dL) {
  int idx = blockIdx.x * 256 + threadIdx.x;
  int c = idx % DM;
  int pl = (idx / DM) & (LL - 1);
  float freq = expf((float)(c & ~1) * (-9.210340371976184f / 768.f));
  float ang = (float)pl * freq;
  float o = out[idx] + ((c & 1) ? cosf(ang) : sinf(ang));
  out[idx] = o;
  unsigned short h, lo;
  split2(o, h, lo);
  dH[idx] = h; dL[idx] = lo;
}

// ---------------------------------------------------------------------------
// MFMA flash attention. grid (qt=8, h=12, b=16), 256 threads / 4 waves.
// Wave w owns q-rows 16w..16w+15 of the 64-row Q tile. Online softmax on the
// MFMA D-layout. All LDS tiles XOR-swizzled (same swz as mgemm). V staged
// transposed (Vt[d][k]) so PV B-frags are contiguous 16B reads.
__global__ __launch_bounds__(256) void flash_kernel(const unsigned short* __restrict__ q,
                                                    const unsigned short* __restrict__ k,
                                                    const unsigned short* __restrict__ v,
                                                    const float* __restrict__ mask,
                                                    unsigned short* __restrict__ OH,
                                                    unsigned short* __restrict__ OL) {
  __shared__ unsigned short Qs_s[64 * 64];
  __shared__ unsigned short Ks_s[64 * 64];
  __shared__ unsigned short Vt_s[64 * 64];
  __shared__ unsigned short Ps_s[64 * 64];
  __shared__ float msk[64];

  const int qt = blockIdx.x, hh = blockIdx.y, b = blockIdx.z;
  const int t = threadIdx.x;
  const int lane = t & 63;
  const int wv = t >> 6;
  const int lr = lane & 15;         // frag row/col index
  const int lk = (lane >> 4) * 8;   // frag k offset
  const int e4 = (lane >> 4) * 4;   // D-layout row base

  // staging map: row sr (0..63; wave w covers its own q-rows), col chunk sc
  const int sr = t >> 2;
  const int sc = (t & 3) * 16;

  // ---- stage Q once, pre-scaled by 1/sqrt(dh)=0.125 (exact exponent shift)
  {
    const size_t g = ((size_t)(b * LL + qt * 64 + sr)) * DM + hh * DH + sc;
    s16x8 q0 = *(const s16x8*)(q + g);
    s16x8 q1 = *(const s16x8*)(q + g + 8);
    s16x8 o0, o1;
#pragma unroll
    for (int i = 0; i < 8; ++i) {
      o0[i] = (short)f2b_rn(braw2f((unsigned short)q0[i]) * 0.125f);
      o1[i] = (short)f2b_rn(braw2f((unsigned short)q1[i]) * 0.125f);
    }
    *(s16x8*)((char*)Qs_s + swz(sr, sc)) = o0;
    *(s16x8*)((char*)Qs_s + swz(sr, sc + 8)) = o1;
  }
  // Q fragments: wave reads only its own rows (staged by its own lanes) —
  // intra-wave lgkmcnt ordering suffices, no barrier needed.
  s16x8 qa0 = *(const s16x8*)((const char*)Qs_s + swz(16 * wv + lr, lk));
  s16x8 qa1 = *(const s16x8*)((const char*)Qs_s + swz(16 * wv + lr, 32 + lk));

  float mrow[4], lrow[4];
  f32x4 oacc[4];
#pragma unroll
  for (int e = 0; e < 4; ++e) { mrow[e] = -1e30f; lrow[e] = 0.f; }
#pragma unroll
  for (int dt = 0; dt < 4; ++dt) oacc[dt] = (f32x4){0.f, 0.f, 0.f, 0.f};

  // prefetch K/V tile 0
  s16x8 kr0, kr1, vr0, vr1;
  float mreg = 0.f;
  {
    const size_t g = ((size_t)(b * LL + sr)) * DM + hh * DH + sc;
    kr0 = *(const s16x8*)(k + g); kr1 = *(const s16x8*)(k + g + 8);
    vr0 = *(const s16x8*)(v + g); vr1 = *(const s16x8*)(v + g + 8);
    if (t < 64) mreg = mask[b * LL + t];
  }

  for (int kt = 0; kt < 8; ++kt) {
    __syncthreads();  // prior iteration's Ks/Vt reads done
    *(s16x8*)((char*)Ks_s + swz(sr, sc)) = kr0;
    *(s16x8*)((char*)Ks_s + swz(sr, sc + 8)) = kr1;
#pragma unroll
    for (int i = 0; i < 8; ++i) {   // transpose-stage V: Vt[d][kpos]
      *(unsigned short*)((char*)Vt_s + swz(sc + i, sr)) = (unsigned short)vr0[i];
      *(unsigned short*)((char*)Vt_s + swz(sc + 8 + i, sr)) = (unsigned short)vr1[i];
    }
    if (t < 64) msk[t] = mreg;
    __syncthreads();
    if (kt < 7) {  // prefetch next tile under compute
      const size_t g = ((size_t)(b * LL + (kt + 1) * 64 + sr)) * DM + hh * DH + sc;
      kr0 = *(const s16x8*)(k + g); kr1 = *(const s16x8*)(k + g + 8);
      vr0 = *(const s16x8*)(v + g); vr1 = *(const s16x8*)(v + g + 8);
      if (t < 64) mreg = mask[b * LL + (kt + 1) * 64 + t];
    }

    // ---- S = Q @ K^T (scaled): 4 col-tiles x 2 k-steps
    f32x4 sacc[4];
#pragma unroll
    for (int ct = 0; ct < 4; ++ct) {
      s16x8 kb0 = *(const s16x8*)((const char*)Ks_s + swz(ct * 16 + lr, lk));
      s16x8 kb1 = *(const s16x8*)((const char*)Ks_s + swz(ct * 16 + lr, 32 + lk));
      sacc[ct] = (f32x4){0.f, 0.f, 0.f, 0.f};
      sacc[ct] = __builtin_amdgcn_mfma_f32_16x16x32_bf16(qa0, kb0, sacc[ct], 0, 0, 0);
      sacc[ct] = __builtin_amdgcn_mfma_f32_16x16x32_bf16(qa1, kb1, sacc[ct], 0, 0, 0);
    }

    // ---- online softmax on D-layout (lane holds 4 rows e, col=ct*16+lr)
    float sv[4][4];
#pragma unroll
    for (int ct = 0; ct < 4; ++ct) {
      float mk = msk[ct * 16 + lr];
#pragma unroll
      for (int e = 0; e < 4; ++e)
        sv[ct][e] = (mk == 0.f) ? -1e9f : sacc[ct][e];
    }
    float rmx[4], al[4], ps[4];
#pragma unroll
    for (int e = 0; e < 4; ++e)
      rmx[e] = fmaxf(fmaxf(sv[0][e], sv[1][e]), fmaxf(sv[2][e], sv[3][e]));
#pragma unroll
    for (int off = 1; off <= 8; off <<= 1)
#pragma unroll
      for (int e = 0; e < 4; ++e) rmx[e] = fmaxf(rmx[e], __shfl_xor(rmx[e], off));
#pragma unroll
    for (int e = 0; e < 4; ++e) {
      float nm = fmaxf(mrow[e], rmx[e]);
      al[e] = __expf(mrow[e] - nm);
      mrow[e] = nm;
      ps[e] = 0.f;
    }
#pragma unroll
    for (int ct = 0; ct < 4; ++ct)
#pragma unroll
      for (int e = 0; e < 4; ++e) {
        float pv = __expf(sv[ct][e] - mrow[e]);
        ps[e] += pv;
        *(unsigned short*)((char*)Ps_s + swz(16 * wv + e4 + e, ct * 16 + lr)) = f2b_rn(pv);
      }
#pragma unroll
    for (int off = 1; off <= 8; off <<= 1)
#pragma unroll
      for (int e = 0; e < 4; ++e) ps[e] += __shfl_xor(ps[e], off);
#pragma unroll
    for (int e = 0; e < 4; ++e) lrow[e] = lrow[e] * al[e] + ps[e];
#pragma unroll
    for (int dt = 0; dt < 4; ++dt)
#pragma unroll
      for (int e = 0; e < 4; ++e) oacc[dt][e] *= al[e];

    // ---- O += P @ V: wave reads only its own Ps rows (self-written)
    s16x8 pa0 = *(const s16x8*)((const char*)Ps_s + swz(16 * wv + lr, lk));
    s16x8 pa1 = *(const s16x8*)((const char*)Ps_s + swz(16 * wv + lr, 32 + lk));
#pragma unroll
    for (int dt = 0; dt < 4; ++dt) {
      s16x8 vb0 = *(const s16x8*)((const char*)Vt_s + swz(dt * 16 + lr, lk));
      s16x8 vb1 = *(const s16x8*)((const char*)Vt_s + swz(dt * 16 + lr, 32 + lk));
      oacc[dt] = __builtin_amdgcn_mfma_f32_16x16x32_bf16(pa0, vb0, oacc[dt], 0, 0, 0);
      oacc[dt] = __builtin_amdgcn_mfma_f32_16x16x32_bf16(pa1, vb1, oacc[dt], 0, 0, 0);
    }
  }

  // ---- epilogue: O/l, split to hi/lo planes
  float inv[4];
#pragma unroll
  for (int e = 0; e < 4; ++e) inv[e] = 1.f / lrow[e];
  const size_t obase = ((size_t)(b * LL + qt * 64 + 16 * wv + e4)) * DM + hh * DH;
#pragma unroll
  for (int dt = 0; dt < 4; ++dt)
#pragma unroll
    for (int e = 0; e < 4; ++e) {
      float val = oacc[dt][e] * inv[e];
      unsigned short h, lo;
      split2(val, h, lo);
      size_t o = obase + (size_t)e * DM + dt * 16 + lr;
      OH[o] = h; OL[o] = lo;
    }
}

// ---------------------------------------------------------------------------
// Final: per-batch gather last valid row, LN, head matmul. Writes FP32 out.
__global__ __launch_bounds__(256) void final_kernel(const float* __restrict__ out,
                                                    const float* __restrict__ mask,
                                                    const float* __restrict__ Wh,
                                                    const float* __restrict__ bh,
                                                    float* __restrict__ dout) {
  __shared__ float rs[256], rq[256];
  const int b = blockIdx.x, t = threadIdx.x;
  rs[t] = mask[b * LL + t] + mask[b * LL + 256 + t];
  __syncthreads();
  for (int off = 128; off; off >>= 1) {
    if (t < off) rs[t] += rs[t + off];
    __syncthreads();
  }
  int idx = (int)(rs[0] + 0.5f) - 1;
  if (idx < 0) idx = 0;
  __syncthreads();

  const float* row = out + ((size_t)b * LL + idx) * DM;
  float x0 = row[t], x1 = row[t + 256], x2 = row[t + 512];
  rs[t] = x0 + x1 + x2;
  rq[t] = x0 * x0 + x1 * x1 + x2 * x2;
  __syncthreads();
  for (int off = 128; off; off >>= 1) {
    if (t < off) { rs[t] += rs[t + off]; rq[t] += rq[t + off]; }
    __syncthreads();
  }
  float mean = rs[0] * (1.f / 768.f);
  float var = rq[0] * (1.f / 768.f) - mean * mean;
  float inv = rsqrtf(var + 1e-5f);
  float y0 = (x0 - mean) * inv, y1 = (x1 - mean) * inv, y2 = (x2 - mean) * inv;
  dout[16 + b * DM + t] = y0;
  dout[16 + b * DM + 256 + t] = y1;
  dout[16 + b * DM + 512 + t] = y2;
  __syncthreads();
  rs[t] = y0 * Wh[t] + y1 * Wh[t + 256] + y2 * Wh[t + 512];
  __syncthreads();
  for (int off = 128; off; off >>= 1) {
    if (t < off) rs[t] += rs[t + off];
    __syncthreads();
  }
  if (t == 0) dout[b] = rs[0] + bh[0];
}

// ---------------------------------------------------------------------------
extern "C" void kernel_launch(void* const* d_in, const int* in_sizes, int n_in,
                              void* d_out, int out_size, void* d_ws, size_t ws_size,
                              hipStream_t stream) {
  const float* ccd    = (const float*)d_in[0];
  const float* mask   = (const float*)d_in[1];
  const float* dkpE   = (const float*)d_in[2];
  const int*   cmask  = (const int*)d_in[3];
  const float* W_gate = (const float*)d_in[4];
  const float* We1 = (const float*)d_in[5];
  const float* be1 = (const float*)d_in[6];
  const float* Weg = (const float*)d_in[7];
  const float* beg = (const float*)d_in[8];
  const float* We2 = (const float*)d_in[9];
  const float* be2 = (const float*)d_in[10];
  const float* Wm1 = (const float*)d_in[11];
  const float* bm1 = (const float*)d_in[12];
  const float* Wmg = (const float*)d_in[13];
  const float* bmg = (const float*)d_in[14];
  const float* Wm2 = (const float*)d_in[15];
  const float* bm2 = (const float*)d_in[16];
  const float* Wq = (const float*)d_in[17];
  const float* Wk = (const float*)d_in[18];
  const float* Wv = (const float*)d_in[19];
  const float* Wo = (const float*)d_in[20];
  const float* bq = (const float*)d_in[21];
  const float* bk = (const float*)d_in[22];
  const float* bv = (const float*)d_in[23];
  const float* bo = (const float*)d_in[24];
  const float* Wf1 = (const float*)d_in[25];
  const float* bf1 = (const float*)d_in[26];
  const float* Wfg = (const float*)d_in[27];
  const float* bfg = (const float*)d_in[28];
  const float* Wf2 = (const float*)d_in[29];
  const float* bf2 = (const float*)d_in[30];
  const float* W_head = (const float*)d_in[31];
  const float* b_head = (const float*)d_in[32];

  // ---- workspace layout (~214 MiB)
  char* base = (char*)d_ws;
  size_t used = 0;
  auto alloc = [&](size_t bytes) -> char* {
    char* r = base + used;
    used += (bytes + 255) & ~(size_t)255;
    return r;
  };
  float* dkp   = (float*)alloc((size_t)8192 * 4);
  float* gates = (float*)alloc((size_t)5 * 16 * DFF * 4);
  float* out   = (float*)alloc((size_t)8192 * DM * 4);
  unsigned short* ubuf = (unsigned short*)alloc((size_t)8192 * DFF * 2);
  unsigned short* AspH = (unsigned short*)alloc((size_t)8192 * 960 * 2);
  unsigned short* AspL = (unsigned short*)alloc((size_t)8192 * 960 * 2);
  const size_t szWe1 = (size_t)3072 * 960;
  const size_t szKN  = (size_t)3072 * 768;
  const size_t szAtt = (size_t)768 * 768;
  unsigned short* We1tH = (unsigned short*)alloc(szWe1 * 2);
  unsigned short* We1tL = (unsigned short*)alloc(szWe1 * 2);
  unsigned short* We2tH = (unsigned short*)alloc(szKN * 2);
  unsigned short* We2tL = (unsigned short*)alloc(szKN * 2);
  unsigned short* Wm1tH = (unsigned short*)alloc(2 * szKN * 2);
  unsigned short* Wm1tL = (unsigned short*)alloc(2 * szKN * 2);
  unsigned short* Wm2tH = (unsigned short*)alloc(2 * szKN * 2);
  unsigned short* Wm2tL = (unsigned short*)alloc(2 * szKN * 2);
  unsigned short* WqtH = (unsigned short*)alloc(2 * szAtt * 2);
  unsigned short* WqtL = (unsigned short*)alloc(2 * szAtt * 2);
  unsigned short* WktH = (unsigned short*)alloc(2 * szAtt * 2);
  unsigned short* WktL = (unsigned short*)alloc(2 * szAtt * 2);
  unsigned short* WvtH = (unsigned short*)alloc(2 * szAtt * 2);
  unsigned short* WvtL = (unsigned short*)alloc(2 * szAtt * 2);
  unsigned short* WotH = (unsigned short*)alloc(2 * szAtt * 2);
  unsigned short* WotL = (unsigned short*)alloc(2 * szAtt * 2);
  unsigned short* Wf1tH = (unsigned short*)alloc(2 * szKN * 2);
  unsigned short* Wf1tL = (unsigned short*)alloc(2 * szKN * 2);
  unsigned short* Wf2tH = (unsigned short*)alloc(2 * szKN * 2);
  unsigned short* Wf2tL = (unsigned short*)alloc(2 * szKN * 2);
  unsigned short* qb = ubuf;                          // aliases: disjoint lifetimes
  unsigned short* kb = ubuf + (size_t)8192 * DM;
  unsigned short* vb = ubuf + (size_t)2 * 8192 * DM;
  if (used > ws_size) return;  // diagnostic: ws too small => output unwritten

  dim3 blk(256);

  // ---- weight prep (transpose + hi/lo split)
  wprep_kernel<<<dim3(30, 96, 1), blk, 0, stream>>>(We1, We1tH, We1tL, 900, 3072, 960);
  wprep_kernel<<<dim3(96, 24, 1), blk, 0, stream>>>(We2, We2tH, We2tL, 3072, 768, 3072);
  wprep_kernel<<<dim3(24, 96, 2), blk, 0, stream>>>(Wm1, Wm1tH, Wm1tL, 768, 3072, 768);
  wprep_kernel<<<dim3(96, 24, 2), blk, 0, stream>>>(Wm2, Wm2tH, Wm2tL, 3072, 768, 3072);
  wprep_kernel<<<dim3(24, 24, 2), blk, 0, stream>>>(Wq, WqtH, WqtL, 768, 768, 768);
  wprep_kernel<<<dim3(24, 24, 2), blk, 0, stream>>>(Wk, WktH, WktL, 768, 768, 768);
  wprep_kernel<<<dim3(24, 24, 2), blk, 0, stream>>>(Wv, WvtH, WvtL, 768, 768, 768);
  wprep_kernel<<<dim3(24, 24, 2), blk, 0, stream>>>(Wo, WotH, WotL, 768, 768, 768);
  wprep_kernel<<<dim3(24, 96, 2), blk, 0, stream>>>(Wf1, Wf1tH, Wf1tL, 768, 3072, 768);
  wprep_kernel<<<dim3(96, 24, 2), blk, 0, stream>>>(Wf2, Wf2tH, Wf2tL, 3072, 768, 3072);

  asplit_kernel<<<30720, blk, 0, stream>>>(ccd, mask, AspH, AspL);

  // gates
  dkp_kernel<<<32, blk, 0, stream>>>(dkpE, W_gate, dkp);
  const float* Wgs[5] = {Weg, Wmg, Wmg + (size_t)GDFF * DFF, Wfg, Wfg + (size_t)GDFF * DFF};
  const float* bgs[5] = {beg, bmg, bmg + DFF, bfg, bfg + DFF};
  for (int g = 0; g < 5; ++g)
    gate_kernel<<<192, blk, 0, stream>>>(dkp, Wgs[g], bgs[g], cmask, gates + (size_t)g * 16 * DFF);

  // patch embed gated FFN
  mgemm_kernel<1, true, unsigned short><<<dim3(24, 64), blk, 0, stream>>>(
      AspH, AspL, We1tH, We1tL, be1, gates, nullptr, ubuf, DFF, 960);
  mgemm_kernel<0, false, float><<<dim3(6, 64), blk, 0, stream>>>(
      ubuf, nullptr, We2tH, We2tL, be2, nullptr, nullptr, out, DM, DFF);

  // intra MLP blocks: out += gated_ffn(ln(out))
  for (int i = 0; i < 2; ++i) {
    ln_kernel<<<8192, blk, 0, stream>>>(out, nullptr, AspH, AspL);
    mgemm_kernel<1, true, unsigned short><<<dim3(24, 64), blk, 0, stream>>>(
        AspH, AspL, Wm1tH + (size_t)i * szKN, Wm1tL + (size_t)i * szKN,
        bm1 + i * DFF, gates + (size_t)(1 + i) * 16 * DFF, nullptr, ubuf, DFF, DM);
    mgemm_kernel<2, false, float><<<dim3(6, 64), blk, 0, stream>>>(
        ubuf, nullptr, Wm2tH + (size_t)i * szKN, Wm2tL + (size_t)i * szKN,
        bm2 + i * DM, nullptr, out, out, DM, DFF);
  }

  pe_kernel<<<24576, blk, 0, stream>>>(out, AspH, AspL);

  // encoder layers
  for (int i = 0; i < 2; ++i) {
    size_t wof = (size_t)i * szAtt;
    mgemm_kernel<0, true, unsigned short><<<dim3(6, 64), blk, 0, stream>>>(
        AspH, AspL, WqtH + wof, WqtL + wof, bq + i * DM, nullptr, nullptr, qb, DM, DM);
    mgemm_kernel<0, true, unsigned short><<<dim3(6, 64), blk, 0, stream>>>(
        AspH, AspL, WktH + wof, WktL + wof, bk + i * DM, nullptr, nullptr, kb, DM, DM);
    mgemm_kernel<0, true, unsigned short><<<dim3(6, 64), blk, 0, stream>>>(
        AspH, AspL, WvtH + wof, WvtL + wof, bv + i * DM, nullptr, nullptr, vb, DM, DM);
    flash_kernel<<<dim3(8, 12, 16), blk, 0, stream>>>(qb, kb, vb, mask, AspH, AspL);
    mgemm_kernel<2, true, float><<<dim3(6, 64), blk, 0, stream>>>(
        AspH, AspL, WotH + wof, WotL + wof, bo + i * DM, nullptr, out, out, DM, DM);
    ln_kernel<<<8192, blk, 0, stream>>>(out, out, AspH, AspL);
    mgemm_kernel<1, true, unsigned short><<<dim3(24, 64), blk, 0, stream>>>(
        AspH, AspL, Wf1tH + (size_t)i * szKN, Wf1tL + (size_t)i * szKN,
        bf1 + i * DFF, gates + (size_t)(3 + i) * 16 * DFF, nullptr, ubuf, DFF, DM);
    mgemm_kernel<2, false, float><<<dim3(6, 64), blk, 0, stream>>>(
        ubuf, nullptr, Wf2tH + (size_t)i * szKN, Wf2tL + (size_t)i * szKN,
        bf2 + i * DM, nullptr, out, out, DM, DFF);
    ln_kernel<<<8192, blk, 0, stream>>>(out, out, AspH, AspL);
  }

  final_kernel<<<16, blk, 0, stream>>>(out, mask, W_head, b_head, (float*)d_out);
}

// Round 4
// 2152.535 us; speedup vs baseline: 3.6159x; 1.0255x over previous
//
#include <hip/hip_runtime.h>
#include <hip/hip_bf16.h>
#include <type_traits>

// Model_50981261804324 — round 10: 32x32x16 MFMA + fused QKV.
// r9 post-mortem: flash MFMA'd (3034->2207us). Top cost now the mgemm family
// (~1.8ms total; big DFF GEMMs 170us each at MfmaUtil 37% = the 2-barrier
// structure ceiling derated by dual-plane LDS traffic). This round:
// (1) inner loop on v_mfma_f32_32x32x16_bf16 (-17% matrix cycles, same LDS);
//     D-layout col=lane&31,row=(reg&3)+8*(reg>>2)+4*(lane>>5) [guide m74/m101].
// (2) fuse Q,K,V GEMMs into one N=2304 GEMM per layer (A read 1x not 3x);
//     flash reads fused buffer with col offsets 0/768/1536, stride 2304.
// Predicted: top mgemm 170->~145us, total ~1900-2000us, absmax 0.015625.

using bf16 = __hip_bfloat16;
using s16x8 = __attribute__((ext_vector_type(8))) short;
using f32x4 = __attribute__((ext_vector_type(4))) float;
using f32x16 = __attribute__((ext_vector_type(16))) float;

#define BB   16
#define LL   512
#define DM   768
#define DFF  3072
#define DLLM 1024
#define GDFF 512
#define NH   12
#define DH   64
#define QS   2304   // fused qkv row stride

__device__ __forceinline__ float braw2f(unsigned short r) {
  union { unsigned u; float f; } c; c.u = ((unsigned)r) << 16; return c.f;
}
__device__ __forceinline__ unsigned short f2b_rn(float x) {
  union { float f; unsigned u; } c; c.f = x;
  unsigned r = c.u + 0x7fffu + ((c.u >> 16) & 1u);
  return (unsigned short)(r >> 16);
}
// split fp32 into hi (truncated bf16, exact) + lo (bf16 of residual)
__device__ __forceinline__ void split2(float v, unsigned short& h, unsigned short& l) {
  union { float f; unsigned u; } c; c.f = v;
  c.u &= 0xffff0000u;
  h = (unsigned short)(c.u >> 16);
  l = f2b_rn(v - c.f);
}
__device__ __forceinline__ float gelu_tanh(float x) {
  float x3 = x * x * x;
  return 0.5f * x * (1.f + tanhf(0.7978845608028654f * (x + 0.044715f * x3)));
}
// LDS byte-offset swizzle: row stride 128B (64 bf16); spreads 8 rows over 8 granules
__device__ __forceinline__ int swz(int r, int k) {
  return ((r << 7) + (k << 1)) ^ ((r & 7) << 4);
}

// ---------------------------------------------------------------------------
__global__ __launch_bounds__(256) void dkp_kernel(const float* __restrict__ E,
                                                  const float* __restrict__ Wg,
                                                  float* __restrict__ dkp) {
  int idx = blockIdx.x * 256 + threadIdx.x;      // 8192
  int b = idx >> 9, n = idx & 511;
  const float* e = E + b * DLLM;
  float acc = 0.f;
  for (int k = 0; k < DLLM; ++k) acc += e[k] * Wg[k * GDFF + n];
  dkp[idx] = acc;
}

__global__ __launch_bounds__(256) void gate_kernel(const float* __restrict__ dkp,
                                                   const float* __restrict__ Wg,
                                                   const float* __restrict__ bg,
                                                   const int* __restrict__ cm,
                                                   float* __restrict__ gout) {
  int idx = blockIdx.x * 256 + threadIdx.x;      // 16*3072
  int b = idx / DFF, n = idx % DFF;
  const float* d = dkp + b * GDFF;
  float acc = 0.f;
  for (int k = 0; k < GDFF; ++k) acc += d[k] * Wg[k * DFF + n];
  acc += bg[n];
  float g = 1.f / (1.f + expf(-acc));
  float km = (n < 1280) ? (float)cm[b * 20 + (n >> 6)] : 1.f;
  gout[idx] = g * km;
}

// pack [bq|bk|bv] per layer into [2][2304]
__global__ __launch_bounds__(256) void packb_kernel(const float* __restrict__ bq,
                                                    const float* __restrict__ bk,
                                                    const float* __restrict__ bv,
                                                    float* __restrict__ dst) {
  int i = blockIdx.x * 256 + threadIdx.x;        // 2*2304
  int l = i / QS, c = i - l * QS;
  float v;
  if (c < 768) v = bq[l * DM + c];
  else if (c < 1536) v = bk[l * DM + c - 768];
  else v = bv[l * DM + c - 1536];
  dst[i] = v;
}

// ---------------------------------------------------------------------------
// Weight prep: W [K][N] fp32 -> Wh,Wl [N][Kpad] bf16 planes (transposed, padded).
__global__ __launch_bounds__(256) void wprep_kernel(const float* __restrict__ W,
                                                    unsigned short* __restrict__ Wh,
                                                    unsigned short* __restrict__ Wl,
                                                    int K, int N, int Kpad) {
  __shared__ float tile[32][33];
  const int z = blockIdx.z;
  W  += (size_t)z * K * N;
  Wh += (size_t)z * N * Kpad;
  Wl += (size_t)z * N * Kpad;
  const int kb = blockIdx.x * 32, nb = blockIdx.y * 32;
  const int tx = threadIdx.x & 31, ty = threadIdx.x >> 5;  // 32 x 8
#pragma unroll
  for (int i = 0; i < 32; i += 8) {
    int k = kb + ty + i;
    tile[ty + i][tx] = (k < K) ? W[(size_t)k * N + nb + tx] : 0.f;
  }
  __syncthreads();
#pragma unroll
  for (int i = 0; i < 32; i += 8) {
    int n = nb + ty + i, k = kb + tx;
    float v = tile[tx][ty + i];
    unsigned short h, l;
    split2(v, h, l);
    size_t o = (size_t)n * Kpad + k;
    Wh[o] = h; Wl[o] = l;
  }
}

// ccd [8192][900] * mask[row] -> AspH/AspL [8192][960] bf16 planes (zero-padded K)
__global__ __launch_bounds__(256) void asplit_kernel(const float* __restrict__ A,
                                                     const float* __restrict__ rs,
                                                     unsigned short* __restrict__ H,
                                                     unsigned short* __restrict__ L) {
  int idx = blockIdx.x * 256 + threadIdx.x;      // 8192*960
  int r = idx / 960, k = idx - r * 960;
  float v = (k < 900) ? A[(size_t)r * 900 + k] * rs[r] : 0.f;
  unsigned short h, l;
  split2(v, h, l);
  H[idx] = h; L[idx] = l;
}

// ---------------------------------------------------------------------------
// Split-bf16 MFMA GEMM on 32x32x16: C[8192,N] = epi(A @ W^T-planes + bias)
template <int MODE, bool ALO, typename CT>
__global__ __launch_bounds__(256) void mgemm_kernel(
    const unsigned short* __restrict__ Ah, const unsigned short* __restrict__ Al,
    const unsigned short* __restrict__ Wh, const unsigned short* __restrict__ Wl,
    const float* __restrict__ bias, const float* __restrict__ gate,
    const float* __restrict__ res, CT* __restrict__ C, int N, int Kpad) {
  __shared__ unsigned short Ah_s[128 * 64];
  __shared__ unsigned short Al_s[ALO ? 128 * 64 : 8];
  __shared__ unsigned short Wh_s[128 * 64];
  __shared__ unsigned short Wl_s[128 * 64];

  const int t = threadIdx.x;
  // XCD-bijective swizzle (all grids have nwg % 8 == 0)
  const int nbx = gridDim.x;
  const int nwg = nbx * gridDim.y;
  int bid = blockIdx.y * nbx + blockIdx.x;
  bid = (bid & 7) * (nwg >> 3) + (bid >> 3);
  const int n0 = (bid % nbx) * 128;
  const int m0 = (bid / nbx) * 128;

  const int lane = t & 63;
  const int wav = t >> 6;
  const int wr = (wav >> 1) * 64;
  const int wc = (wav & 1) * 64;
  const int l32 = lane & 31;       // 32x32 frag row/col
  const int k8 = (lane >> 5) * 8;  // 32x32 frag k offset
  const int sr = t >> 3;           // staging row 0..31 (+32*it)
  const int sk = (t & 7) * 8;      // staging k 0..56

  f32x16 acc[2][2];
#pragma unroll
  for (int i = 0; i < 2; ++i)
#pragma unroll
    for (int j = 0; j < 2; ++j)
#pragma unroll
      for (int r = 0; r < 16; ++r) acc[i][j][r] = 0.f;

  s16x8 va[4], val[4], vw[4], vwl[4];
  auto load_tile = [&](int k0) {
#pragma unroll
    for (int it = 0; it < 4; ++it) {
      const int r = sr + it * 32;
      const size_t gw = (size_t)(n0 + r) * Kpad + (k0 + sk);
      const size_t ga = (size_t)(m0 + r) * Kpad + (k0 + sk);
      vw[it]  = *(const s16x8*)(Wh + gw);
      vwl[it] = *(const s16x8*)(Wl + gw);
      va[it]  = *(const s16x8*)(Ah + ga);
      if constexpr (ALO) val[it] = *(const s16x8*)(Al + ga);
    }
  };
  load_tile(0);

  for (int k0 = 0; k0 < Kpad; k0 += 64) {
    __syncthreads();   // previous compute's LDS reads done
#pragma unroll
    for (int it = 0; it < 4; ++it) {
      const int so = swz(sr + it * 32, sk);
      *(s16x8*)((char*)Wh_s + so) = vw[it];
      *(s16x8*)((char*)Wl_s + so) = vwl[it];
      *(s16x8*)((char*)Ah_s + so) = va[it];
      if constexpr (ALO) *(s16x8*)((char*)Al_s + so) = val[it];
    }
    __syncthreads();
    if (k0 + 64 < Kpad) load_tile(k0 + 64);  // prefetch hides under MFMA

#pragma unroll
    for (int kk = 0; kk < 64; kk += 16) {
      s16x8 fa[2], fal[2], fwh[2], fwl[2];
#pragma unroll
      for (int f = 0; f < 2; ++f) {
        fwh[f] = *(const s16x8*)((const char*)Wh_s + swz(wc + f * 32 + l32, kk + k8));
        fwl[f] = *(const s16x8*)((const char*)Wl_s + swz(wc + f * 32 + l32, kk + k8));
        fa[f]  = *(const s16x8*)((const char*)Ah_s + swz(wr + f * 32 + l32, kk + k8));
        if constexpr (ALO)
          fal[f] = *(const s16x8*)((const char*)Al_s + swz(wr + f * 32 + l32, kk + k8));
      }
#pragma unroll
      for (int i = 0; i < 2; ++i)
#pragma unroll
        for (int j = 0; j < 2; ++j) {
          acc[i][j] = __builtin_amdgcn_mfma_f32_32x32x16_bf16(fa[i], fwh[j], acc[i][j], 0, 0, 0);
          acc[i][j] = __builtin_amdgcn_mfma_f32_32x32x16_bf16(fa[i], fwl[j], acc[i][j], 0, 0, 0);
          if constexpr (ALO)
            acc[i][j] = __builtin_amdgcn_mfma_f32_32x32x16_bf16(fal[i], fwh[j], acc[i][j], 0, 0, 0);
        }
    }
  }

  // epilogue: 32x32 D layout: col=lane&31, row=(reg&3)+8*(reg>>2)+4*(lane>>5)
  const int rb = (lane >> 5) * 4;
  const int gb = (m0 >> 9) * DFF;   // 128-row tile lies in one batch
#pragma unroll
  for (int i = 0; i < 2; ++i) {
#pragma unroll
    for (int j = 0; j < 2; ++j) {
      const int gc = n0 + wc + j * 32 + l32;
      const float bb = bias[gc];
#pragma unroll
      for (int r = 0; r < 16; ++r) {
        const int gr = m0 + wr + i * 32 + (r & 3) + 8 * (r >> 2) + rb;
        float v = acc[i][j][r] + bb;
        if constexpr (MODE == 1) v = gelu_tanh(v) * gate[gb + gc];
        if constexpr (MODE == 2) v += res[(size_t)gr * N + gc];
        if constexpr (std::is_same<CT, float>::value) C[(size_t)gr * N + gc] = v;
        else C[(size_t)gr * N + gc] = f2b_rn(v);
      }
    }
  }
}

// ---------------------------------------------------------------------------
// LayerNorm; optionally writes fp32 and always writes split bf16 planes.
__global__ __launch_bounds__(256) void ln_kernel(const float* __restrict__ src,
                                                 float* __restrict__ dstF,
                                                 unsigned short* __restrict__ dH,
                                                 unsigned short* __restrict__ dL) {
  __shared__ float rs_[256], rq_[256];
  const int row = blockIdx.x, t = threadIdx.x;
  const float* p = src + (size_t)row * DM;
  float x0 = p[t], x1 = p[t + 256], x2 = p[t + 512];
  rs_[t] = x0 + x1 + x2;
  rq_[t] = x0 * x0 + x1 * x1 + x2 * x2;
  __syncthreads();
  for (int off = 128; off; off >>= 1) {
    if (t < off) { rs_[t] += rs_[t + off]; rq_[t] += rq_[t + off]; }
    __syncthreads();
  }
  float mean = rs_[0] * (1.f / 768.f);
  float var = rq_[0] * (1.f / 768.f) - mean * mean;
  float inv = rsqrtf(var + 1e-5f);
  float y0 = (x0 - mean) * inv, y1 = (x1 - mean) * inv, y2 = (x2 - mean) * inv;
  if (dstF) {
    float* q = dstF + (size_t)row * DM;
    q[t] = y0; q[t + 256] = y1; q[t + 512] = y2;
  }
  const size_t base = (size_t)row * DM;
  unsigned short h, lo;
  split2(y0, h, lo); dH[base + t] = h;       dL[base + t] = lo;
  split2(y1, h, lo); dH[base + t + 256] = h; dL[base + t + 256] = lo;
  split2(y2, h, lo); dH[base + t + 512] = h; dL[base + t + 512] = lo;
}

// out += sinusoidal PE; also writes split planes (feeds layer-0 QKV GEMM)
__global__ __launch_bounds__(256) void pe_kernel(float* __restrict__ out,
                                                 unsigned short* __restrict__ dH,
                                                 unsigned short* __restrict__ dL) {
  int idx = blockIdx.x * 256 + threadIdx.x;
  int c = idx % DM;
  int pl = (idx / DM) & (LL - 1);
  float freq = expf((float)(c & ~1) * (-9.210340371976184f / 768.f));
  float ang = (float)pl * freq;
  float o = out[idx] + ((c & 1) ? cosf(ang) : sinf(ang));
  out[idx] = o;
  unsigned short h, lo;
  split2(o, h, lo);
  dH[idx] = h; dL[idx] = lo;
}

// ---------------------------------------------------------------------------
// MFMA flash attention reading fused qkv buffer [8192][2304] (q|k|v).
__global__ __launch_bounds__(256) void flash_kernel(const unsigned short* __restrict__ qkv,
                                                    const float* __restrict__ mask,
                                                    unsigned short* __restrict__ OH,
                                                    unsigned short* __restrict__ OL) {
  __shared__ unsigned short Qs_s[64 * 64];
  __shared__ unsigned short Ks_s[64 * 64];
  __shared__ unsigned short Vt_s[64 * 64];
  __shared__ unsigned short Ps_s[64 * 64];
  __shared__ float msk[64];

  const int qt = blockIdx.x, hh = blockIdx.y, b = blockIdx.z;
  const int t = threadIdx.x;
  const int lane = t & 63;
  const int wv = t >> 6;
  const int lr = lane & 15;         // frag row/col index
  const int lk = (lane >> 4) * 8;   // frag k offset
  const int e4 = (lane >> 4) * 4;   // D-layout row base

  const int sr = t >> 2;
  const int sc = (t & 3) * 16;

  // ---- stage Q once, pre-scaled by 1/sqrt(dh)=0.125 (exact exponent shift)
  {
    const size_t g = ((size_t)(b * LL + qt * 64 + sr)) * QS + hh * DH + sc;
    s16x8 q0 = *(const s16x8*)(qkv + g);
    s16x8 q1 = *(const s16x8*)(qkv + g + 8);
    s16x8 o0, o1;
#pragma unroll
    for (int i = 0; i < 8; ++i) {
      o0[i] = (short)f2b_rn(braw2f((unsigned short)q0[i]) * 0.125f);
      o1[i] = (short)f2b_rn(braw2f((unsigned short)q1[i]) * 0.125f);
    }
    *(s16x8*)((char*)Qs_s + swz(sr, sc)) = o0;
    *(s16x8*)((char*)Qs_s + swz(sr, sc + 8)) = o1;
  }
  // wave reads only its own rows (staged by its own lanes): no barrier needed
  s16x8 qa0 = *(const s16x8*)((const char*)Qs_s + swz(16 * wv + lr, lk));
  s16x8 qa1 = *(const s16x8*)((const char*)Qs_s + swz(16 * wv + lr, 32 + lk));

  float mrow[4], lrow[4];
  f32x4 oacc[4];
#pragma unroll
  for (int e = 0; e < 4; ++e) { mrow[e] = -1e30f; lrow[e] = 0.f; }
#pragma unroll
  for (int dt = 0; dt < 4; ++dt) oacc[dt] = (f32x4){0.f, 0.f, 0.f, 0.f};

  // prefetch K/V tile 0 (k at col +768, v at +1536 of fused buffer)
  s16x8 kr0, kr1, vr0, vr1;
  float mreg = 0.f;
  {
    const size_t g = ((size_t)(b * LL + sr)) * QS + hh * DH + sc;
    kr0 = *(const s16x8*)(qkv + g + 768); kr1 = *(const s16x8*)(qkv + g + 776);
    vr0 = *(const s16x8*)(qkv + g + 1536); vr1 = *(const s16x8*)(qkv + g + 1544);
    if (t < 64) mreg = mask[b * LL + t];
  }

  for (int kt = 0; kt < 8; ++kt) {
    __syncthreads();  // prior iteration's Ks/Vt reads done
    *(s16x8*)((char*)Ks_s + swz(sr, sc)) = kr0;
    *(s16x8*)((char*)Ks_s + swz(sr, sc + 8)) = kr1;
#pragma unroll
    for (int i = 0; i < 8; ++i) {   // transpose-stage V: Vt[d][kpos]
      *(unsigned short*)((char*)Vt_s + swz(sc + i, sr)) = (unsigned short)vr0[i];
      *(unsigned short*)((char*)Vt_s + swz(sc + 8 + i, sr)) = (unsigned short)vr1[i];
    }
    if (t < 64) msk[t] = mreg;
    __syncthreads();
    if (kt < 7) {  // prefetch next tile under compute
      const size_t g = ((size_t)(b * LL + (kt + 1) * 64 + sr)) * QS + hh * DH + sc;
      kr0 = *(const s16x8*)(qkv + g + 768); kr1 = *(const s16x8*)(qkv + g + 776);
      vr0 = *(const s16x8*)(qkv + g + 1536); vr1 = *(const s16x8*)(qkv + g + 1544);
      if (t < 64) mreg = mask[b * LL + (kt + 1) * 64 + t];
    }

    // ---- S = Q @ K^T (scaled): 4 col-tiles x 2 k-steps
    f32x4 sacc[4];
#pragma unroll
    for (int ct = 0; ct < 4; ++ct) {
      s16x8 kb0 = *(const s16x8*)((const char*)Ks_s + swz(ct * 16 + lr, lk));
      s16x8 kb1 = *(const s16x8*)((const char*)Ks_s + swz(ct * 16 + lr, 32 + lk));
      sacc[ct] = (f32x4){0.f, 0.f, 0.f, 0.f};
      sacc[ct] = __builtin_amdgcn_mfma_f32_16x16x32_bf16(qa0, kb0, sacc[ct], 0, 0, 0);
      sacc[ct] = __builtin_amdgcn_mfma_f32_16x16x32_bf16(qa1, kb1, sacc[ct], 0, 0, 0);
    }

    // ---- online softmax on D-layout (lane holds 4 rows e, col=ct*16+lr)
    float sv[4][4];
#pragma unroll
    for (int ct = 0; ct < 4; ++ct) {
      float mk = msk[ct * 16 + lr];
#pragma unroll
      for (int e = 0; e < 4; ++e)
        sv[ct][e] = (mk == 0.f) ? -1e9f : sacc[ct][e];
    }
    float rmx[4], al[4], ps[4];
#pragma unroll
    for (int e = 0; e < 4; ++e)
      rmx[e] = fmaxf(fmaxf(sv[0][e], sv[1][e]), fmaxf(sv[2][e], sv[3][e]));
#pragma unroll
    for (int off = 1; off <= 8; off <<= 1)
#pragma unroll
      for (int e = 0; e < 4; ++e) rmx[e] = fmaxf(rmx[e], __shfl_xor(rmx[e], off));
#pragma unroll
    for (int e = 0; e < 4; ++e) {
      float nm = fmaxf(mrow[e], rmx[e]);
      al[e] = __expf(mrow[e] - nm);
      mrow[e] = nm;
      ps[e] = 0.f;
    }
#pragma unroll
    for (int ct = 0; ct < 4; ++ct)
#pragma unroll
      for (int e = 0; e < 4; ++e) {
        float pv = __expf(sv[ct][e] - mrow[e]);
        ps[e] += pv;
        *(unsigned short*)((char*)Ps_s + swz(16 * wv + e4 + e, ct * 16 + lr)) = f2b_rn(pv);
      }
#pragma unroll
    for (int off = 1; off <= 8; off <<= 1)
#pragma unroll
      for (int e = 0; e < 4; ++e) ps[e] += __shfl_xor(ps[e], off);
#pragma unroll
    for (int e = 0; e < 4; ++e) lrow[e] = lrow[e] * al[e] + ps[e];
#pragma unroll
    for (int dt = 0; dt < 4; ++dt)
#pragma unroll
      for (int e = 0; e < 4; ++e) oacc[dt][e] *= al[e];

    // ---- O += P @ V: wave reads only its own Ps rows (self-written)
    s16x8 pa0 = *(const s16x8*)((const char*)Ps_s + swz(16 * wv + lr, lk));
    s16x8 pa1 = *(const s16x8*)((const char*)Ps_s + swz(16 * wv + lr, 32 + lk));
#pragma unroll
    for (int dt = 0; dt < 4; ++dt) {
      s16x8 vb0 = *(const s16x8*)((const char*)Vt_s + swz(dt * 16 + lr, lk));
      s16x8 vb1 = *(const s16x8*)((const char*)Vt_s + swz(dt * 16 + lr, 32 + lk));
      oacc[dt] = __builtin_amdgcn_mfma_f32_16x16x32_bf16(pa0, vb0, oacc[dt], 0, 0, 0);
      oacc[dt] = __builtin_amdgcn_mfma_f32_16x16x32_bf16(pa1, vb1, oacc[dt], 0, 0, 0);
    }
  }

  // ---- epilogue: O/l, split to hi/lo planes (dense [8192][768] layout)
  float inv[4];
#pragma unroll
  for (int e = 0; e < 4; ++e) inv[e] = 1.f / lrow[e];
  const size_t obase = ((size_t)(b * LL + qt * 64 + 16 * wv + e4)) * DM + hh * DH;
#pragma unroll
  for (int dt = 0; dt < 4; ++dt)
#pragma unroll
    for (int e = 0; e < 4; ++e) {
      float val = oacc[dt][e] * inv[e];
      unsigned short h, lo;
      split2(val, h, lo);
      size_t o = obase + (size_t)e * DM + dt * 16 + lr;
      OH[o] = h; OL[o] = lo;
    }
}

// ---------------------------------------------------------------------------
// Final: per-batch gather last valid row, LN, head matmul. Writes FP32 out.
__global__ __launch_bounds__(256) void final_kernel(const float* __restrict__ out,
                                                    const float* __restrict__ mask,
                                                    const float* __restrict__ Wh,
                                                    const float* __restrict__ bh,
                                                    float* __restrict__ dout) {
  __shared__ float rs[256], rq[256];
  const int b = blockIdx.x, t = threadIdx.x;
  rs[t] = mask[b * LL + t] + mask[b * LL + 256 + t];
  __syncthreads();
  for (int off = 128; off; off >>= 1) {
    if (t < off) rs[t] += rs[t + off];
    __syncthreads();
  }
  int idx = (int)(rs[0] + 0.5f) - 1;
  if (idx < 0) idx = 0;
  __syncthreads();

  const float* row = out + ((size_t)b * LL + idx) * DM;
  float x0 = row[t], x1 = row[t + 256], x2 = row[t + 512];
  rs[t] = x0 + x1 + x2;
  rq[t] = x0 * x0 + x1 * x1 + x2 * x2;
  __syncthreads();
  for (int off = 128; off; off >>= 1) {
    if (t < off) { rs[t] += rs[t + off]; rq[t] += rq[t + off]; }
    __syncthreads();
  }
  float mean = rs[0] * (1.f / 768.f);
  float var = rq[0] * (1.f / 768.f) - mean * mean;
  float inv = rsqrtf(var + 1e-5f);
  float y0 = (x0 - mean) * inv, y1 = (x1 - mean) * inv, y2 = (x2 - mean) * inv;
  dout[16 + b * DM + t] = y0;
  dout[16 + b * DM + 256 + t] = y1;
  dout[16 + b * DM + 512 + t] = y2;
  __syncthreads();
  rs[t] = y0 * Wh[t] + y1 * Wh[t + 256] + y2 * Wh[t + 512];
  __syncthreads();
  for (int off = 128; off; off >>= 1) {
    if (t < off) rs[t] += rs[t + off];
    __syncthreads();
  }
  if (t == 0) dout[b] = rs[0] + bh[0];
}

// ---------------------------------------------------------------------------
extern "C" void kernel_launch(void* const* d_in, const int* in_sizes, int n_in,
                              void* d_out, int out_size, void* d_ws, size_t ws_size,
                              hipStream_t stream) {
  const float* ccd    = (const float*)d_in[0];
  const float* mask   = (const float*)d_in[1];
  const float* dkpE   = (const float*)d_in[2];
  const int*   cmask  = (const int*)d_in[3];
  const float* W_gate = (const float*)d_in[4];
  const float* We1 = (const float*)d_in[5];
  const float* be1 = (const float*)d_in[6];
  const float* Weg = (const float*)d_in[7];
  const float* beg = (const float*)d_in[8];
  const float* We2 = (const float*)d_in[9];
  const float* be2 = (const float*)d_in[10];
  const float* Wm1 = (const float*)d_in[11];
  const float* bm1 = (const float*)d_in[12];
  const float* Wmg = (const float*)d_in[13];
  const float* bmg = (const float*)d_in[14];
  const float* Wm2 = (const float*)d_in[15];
  const float* bm2 = (const float*)d_in[16];
  const float* Wq = (const float*)d_in[17];
  const float* Wk = (const float*)d_in[18];
  const float* Wv = (const float*)d_in[19];
  const float* Wo = (const float*)d_in[20];
  const float* bq = (const float*)d_in[21];
  const float* bk = (const float*)d_in[22];
  const float* bv = (const float*)d_in[23];
  const float* bo = (const float*)d_in[24];
  const float* Wf1 = (const float*)d_in[25];
  const float* bf1 = (const float*)d_in[26];
  const float* Wfg = (const float*)d_in[27];
  const float* bfg = (const float*)d_in[28];
  const float* Wf2 = (const float*)d_in[29];
  const float* bf2 = (const float*)d_in[30];
  const float* W_head = (const float*)d_in[31];
  const float* b_head = (const float*)d_in[32];

  // ---- workspace layout (~214 MiB)
  char* base = (char*)d_ws;
  size_t used = 0;
  auto alloc = [&](size_t bytes) -> char* {
    char* r = base + used;
    used += (bytes + 255) & ~(size_t)255;
    return r;
  };
  float* dkp   = (float*)alloc((size_t)8192 * 4);
  float* gates = (float*)alloc((size_t)5 * 16 * DFF * 4);
  float* qkvb  = (float*)alloc((size_t)2 * QS * 4);
  float* out   = (float*)alloc((size_t)8192 * DM * 4);
  unsigned short* ubuf = (unsigned short*)alloc((size_t)8192 * DFF * 2);
  unsigned short* AspH = (unsigned short*)alloc((size_t)8192 * 960 * 2);
  unsigned short* AspL = (unsigned short*)alloc((size_t)8192 * 960 * 2);
  const size_t szWe1 = (size_t)3072 * 960;
  const size_t szKN  = (size_t)3072 * 768;
  const size_t szAtt = (size_t)768 * 768;
  const size_t szQKV = (size_t)QS * 768;         // per-layer fused qkv planes
  unsigned short* We1tH = (unsigned short*)alloc(szWe1 * 2);
  unsigned short* We1tL = (unsigned short*)alloc(szWe1 * 2);
  unsigned short* We2tH = (unsigned short*)alloc(szKN * 2);
  unsigned short* We2tL = (unsigned short*)alloc(szKN * 2);
  unsigned short* Wm1tH = (unsigned short*)alloc(2 * szKN * 2);
  unsigned short* Wm1tL = (unsigned short*)alloc(2 * szKN * 2);
  unsigned short* Wm2tH = (unsigned short*)alloc(2 * szKN * 2);
  unsigned short* Wm2tL = (unsigned short*)alloc(2 * szKN * 2);
  unsigned short* WqkvH = (unsigned short*)alloc(2 * szQKV * 2);
  unsigned short* WqkvL = (unsigned short*)alloc(2 * szQKV * 2);
  unsigned short* WotH = (unsigned short*)alloc(2 * szAtt * 2);
  unsigned short* WotL = (unsigned short*)alloc(2 * szAtt * 2);
  unsigned short* Wf1tH = (unsigned short*)alloc(2 * szKN * 2);
  unsigned short* Wf1tL = (unsigned short*)alloc(2 * szKN * 2);
  unsigned short* Wf2tH = (unsigned short*)alloc(2 * szKN * 2);
  unsigned short* Wf2tL = (unsigned short*)alloc(2 * szKN * 2);
  if (used > ws_size) return;  // diagnostic: ws too small => output unwritten

  dim3 blk(256);

  // ---- weight prep (transpose + hi/lo split)
  wprep_kernel<<<dim3(30, 96, 1), blk, 0, stream>>>(We1, We1tH, We1tL, 900, 3072, 960);
  wprep_kernel<<<dim3(96, 24, 1), blk, 0, stream>>>(We2, We2tH, We2tL, 3072, 768, 3072);
  wprep_kernel<<<dim3(24, 96, 2), blk, 0, stream>>>(Wm1, Wm1tH, Wm1tL, 768, 3072, 768);
  wprep_kernel<<<dim3(96, 24, 2), blk, 0, stream>>>(Wm2, Wm2tH, Wm2tL, 3072, 768, 3072);
  for (int i = 0; i < 2; ++i) {   // fused qkv weight planes: rows q|k|v per layer
    wprep_kernel<<<dim3(24, 24, 1), blk, 0, stream>>>(
        Wq + (size_t)i * szAtt, WqkvH + (size_t)i * szQKV, WqkvL + (size_t)i * szQKV, 768, 768, 768);
    wprep_kernel<<<dim3(24, 24, 1), blk, 0, stream>>>(
        Wk + (size_t)i * szAtt, WqkvH + (size_t)i * szQKV + (size_t)768 * 768,
        WqkvL + (size_t)i * szQKV + (size_t)768 * 768, 768, 768, 768);
    wprep_kernel<<<dim3(24, 24, 1), blk, 0, stream>>>(
        Wv + (size_t)i * szAtt, WqkvH + (size_t)i * szQKV + (size_t)1536 * 768,
        WqkvL + (size_t)i * szQKV + (size_t)1536 * 768, 768, 768, 768);
  }
  wprep_kernel<<<dim3(24, 24, 2), blk, 0, stream>>>(Wo, WotH, WotL, 768, 768, 768);
  wprep_kernel<<<dim3(24, 96, 2), blk, 0, stream>>>(Wf1, Wf1tH, Wf1tL, 768, 3072, 768);
  wprep_kernel<<<dim3(96, 24, 2), blk, 0, stream>>>(Wf2, Wf2tH, Wf2tL, 3072, 768, 3072);

  asplit_kernel<<<30720, blk, 0, stream>>>(ccd, mask, AspH, AspL);
  packb_kernel<<<18, blk, 0, stream>>>(bq, bk, bv, qkvb);

  // gates
  dkp_kernel<<<32, blk, 0, stream>>>(dkpE, W_gate, dkp);
  const float* Wgs[5] = {Weg, Wmg, Wmg + (size_t)GDFF * DFF, Wfg, Wfg + (size_t)GDFF * DFF};
  const float* bgs[5] = {beg, bmg, bmg + DFF, bfg, bfg + DFF};
  for (int g = 0; g < 5; ++g)
    gate_kernel<<<192, blk, 0, stream>>>(dkp, Wgs[g], bgs[g], cmask, gates + (size_t)g * 16 * DFF);

  // patch embed gated FFN
  mgemm_kernel<1, true, unsigned short><<<dim3(24, 64), blk, 0, stream>>>(
      AspH, AspL, We1tH, We1tL, be1, gates, nullptr, ubuf, DFF, 960);
  mgemm_kernel<0, false, float><<<dim3(6, 64), blk, 0, stream>>>(
      ubuf, nullptr, We2tH, We2tL, be2, nullptr, nullptr, out, DM, DFF);

  // intra MLP blocks: out += gated_ffn(ln(out))
  for (int i = 0; i < 2; ++i) {
    ln_kernel<<<8192, blk, 0, stream>>>(out, nullptr, AspH, AspL);
    mgemm_kernel<1, true, unsigned short><<<dim3(24, 64), blk, 0, stream>>>(
        AspH, AspL, Wm1tH + (size_t)i * szKN, Wm1tL + (size_t)i * szKN,
        bm1 + i * DFF, gates + (size_t)(1 + i) * 16 * DFF, nullptr, ubuf, DFF, DM);
    mgemm_kernel<2, false, float><<<dim3(6, 64), blk, 0, stream>>>(
        ubuf, nullptr, Wm2tH + (size_t)i * szKN, Wm2tL + (size_t)i * szKN,
        bm2 + i * DM, nullptr, out, out, DM, DFF);
  }

  pe_kernel<<<24576, blk, 0, stream>>>(out, AspH, AspL);

  // encoder layers
  for (int i = 0; i < 2; ++i) {
    // fused QKV: [8192][2304] = A @ [Wq|Wk|Wv]^T
    mgemm_kernel<0, true, unsigned short><<<dim3(18, 64), blk, 0, stream>>>(
        AspH, AspL, WqkvH + (size_t)i * szQKV, WqkvL + (size_t)i * szQKV,
        qkvb + (size_t)i * QS, nullptr, nullptr, ubuf, QS, DM);
    flash_kernel<<<dim3(8, 12, 16), blk, 0, stream>>>(ubuf, mask, AspH, AspL);
    mgemm_kernel<2, true, float><<<dim3(6, 64), blk, 0, stream>>>(
        AspH, AspL, WotH + (size_t)i * szAtt, WotL + (size_t)i * szAtt,
        bo + i * DM, nullptr, out, out, DM, DM);
    ln_kernel<<<8192, blk, 0, stream>>>(out, out, AspH, AspL);
    mgemm_kernel<1, true, unsigned short><<<dim3(24, 64), blk, 0, stream>>>(
        AspH, AspL, Wf1tH + (size_t)i * szKN, Wf1tL + (size_t)i * szKN,
        bf1 + i * DFF, gates + (size_t)(3 + i) * 16 * DFF, nullptr, ubuf, DFF, DM);
    mgemm_kernel<2, false, float><<<dim3(6, 64), blk, 0, stream>>>(
        ubuf, nullptr, Wf2tH + (size_t)i * szKN, Wf2tL + (size_t)i * szKN,
        bf2 + i * DM, nullptr, out, out, DM, DFF);
    ln_kernel<<<8192, blk, 0, stream>>>(out, out, AspH, AspL);
  }

  final_kernel<<<16, blk, 0, stream>>>(out, mask, W_head, b_head, (float*)d_out);
}

// Round 5
// 1948.854 us; speedup vs baseline: 3.9938x; 1.1045x over previous
//
#include <hip/hip_runtime.h>
#include <hip/hip_bf16.h>
#include <type_traits>

// Model_50981261804324 — round 11: fp16 planes, 2-term GEMMs, 16x16 revert.
// r10 post-mortem: 32x32 frag reads alias 4-way under the 8-row XOR swizzle
// (1.18e7 conflicts, 170->177us) — reverted to the proven conflict-free 16x16
// pattern. QKV fusion kept (it delivered r10's net win).
// This round's lever: all staging planes bf16 -> fp16 (10-bit mantissa).
// Weights stay 2-plane (err ~2^-19); activations drop to ONE plane (2^-11,
// vs bf16 2-plane's 2^-16 — but pipeline error was dominated by bf16 ubuf/qkv
// staging at 2^-8 anyway, which now improves 8x). Every GEMM becomes 2-term:
// LDS reads 12/kk (was 16), MFMA 32/kk (was 48), staging 3 planes (was 4),
// LDS 48KB/block -> 3 blocks/CU. Predicted: big GEMM 177->~120us, conflicts ~0,
// total ~1600-1750us, absmax DROPS to ~0.002-0.008.

using bf16 = __hip_bfloat16;
using h16x8 = __attribute__((ext_vector_type(8))) _Float16;
using f32x4 = __attribute__((ext_vector_type(4))) float;

#define BB   16
#define LL   512
#define DM   768
#define DFF  3072
#define DLLM 1024
#define GDFF 512
#define NH   12
#define DH   64
#define QS   2304   // fused qkv row stride

__device__ __forceinline__ unsigned short f2h(float x) {
  union { _Float16 h; unsigned short u; } c; c.h = (_Float16)x; return c.u;
}
__device__ __forceinline__ float h2f(unsigned short r) {
  union { _Float16 h; unsigned short u; } c; c.u = r; return (float)c.h;
}
// split fp32 into hi (fp16 RN) + lo (fp16 of residual): combined ~2^-21
__device__ __forceinline__ void split2h(float v, unsigned short& h, unsigned short& l) {
  union { _Float16 h; unsigned short u; } c;
  _Float16 hh = (_Float16)v;
  c.h = hh; h = c.u;
  c.h = (_Float16)(v - (float)hh); l = c.u;
}
__device__ __forceinline__ float gelu_tanh(float x) {
  float x3 = x * x * x;
  return 0.5f * x * (1.f + tanhf(0.7978845608028654f * (x + 0.044715f * x3)));
}
// LDS byte-offset swizzle: row stride 128B (64 fp16); spreads 8 rows over 8 granules
__device__ __forceinline__ int swz(int r, int k) {
  return ((r << 7) + (k << 1)) ^ ((r & 7) << 4);
}

// ---------------------------------------------------------------------------
__global__ __launch_bounds__(256) void dkp_kernel(const float* __restrict__ E,
                                                  const float* __restrict__ Wg,
                                                  float* __restrict__ dkp) {
  int idx = blockIdx.x * 256 + threadIdx.x;      // 8192
  int b = idx >> 9, n = idx & 511;
  const float* e = E + b * DLLM;
  float acc = 0.f;
  for (int k = 0; k < DLLM; ++k) acc += e[k] * Wg[k * GDFF + n];
  dkp[idx] = acc;
}

__global__ __launch_bounds__(256) void gate_kernel(const float* __restrict__ dkp,
                                                   const float* __restrict__ Wg,
                                                   const float* __restrict__ bg,
                                                   const int* __restrict__ cm,
                                                   float* __restrict__ gout) {
  int idx = blockIdx.x * 256 + threadIdx.x;      // 16*3072
  int b = idx / DFF, n = idx % DFF;
  const float* d = dkp + b * GDFF;
  float acc = 0.f;
  for (int k = 0; k < GDFF; ++k) acc += d[k] * Wg[k * DFF + n];
  acc += bg[n];
  float g = 1.f / (1.f + expf(-acc));
  float km = (n < 1280) ? (float)cm[b * 20 + (n >> 6)] : 1.f;
  gout[idx] = g * km;
}

// pack [bq|bk|bv] per layer into [2][2304]
__global__ __launch_bounds__(256) void packb_kernel(const float* __restrict__ bq,
                                                    const float* __restrict__ bk,
                                                    const float* __restrict__ bv,
                                                    float* __restrict__ dst) {
  int i = blockIdx.x * 256 + threadIdx.x;        // 2*2304
  int l = i / QS, c = i - l * QS;
  float v;
  if (c < 768) v = bq[l * DM + c];
  else if (c < 1536) v = bk[l * DM + c - 768];
  else v = bv[l * DM + c - 1536];
  dst[i] = v;
}

// ---------------------------------------------------------------------------
// Weight prep: W [K][N] fp32 -> Wh,Wl [N][Kpad] fp16 planes (transposed, padded).
__global__ __launch_bounds__(256) void wprep_kernel(const float* __restrict__ W,
                                                    unsigned short* __restrict__ Wh,
                                                    unsigned short* __restrict__ Wl,
                                                    int K, int N, int Kpad) {
  __shared__ float tile[32][33];
  const int z = blockIdx.z;
  W  += (size_t)z * K * N;
  Wh += (size_t)z * N * Kpad;
  Wl += (size_t)z * N * Kpad;
  const int kb = blockIdx.x * 32, nb = blockIdx.y * 32;
  const int tx = threadIdx.x & 31, ty = threadIdx.x >> 5;  // 32 x 8
#pragma unroll
  for (int i = 0; i < 32; i += 8) {
    int k = kb + ty + i;
    tile[ty + i][tx] = (k < K) ? W[(size_t)k * N + nb + tx] : 0.f;
  }
  __syncthreads();
#pragma unroll
  for (int i = 0; i < 32; i += 8) {
    int n = nb + ty + i, k = kb + tx;
    unsigned short h, l;
    split2h(tile[tx][ty + i], h, l);
    size_t o = (size_t)n * Kpad + k;
    Wh[o] = h; Wl[o] = l;
  }
}

// ccd [8192][900] * mask[row] -> AspH [8192][960] fp16 plane (zero-padded K)
__global__ __launch_bounds__(256) void asplit_kernel(const float* __restrict__ A,
                                                     const float* __restrict__ rs,
                                                     unsigned short* __restrict__ H) {
  int idx = blockIdx.x * 256 + threadIdx.x;      // 8192*960
  int r = idx / 960, k = idx - r * 960;
  float v = (k < 900) ? A[(size_t)r * 900 + k] * rs[r] : 0.f;
  H[idx] = f2h(v);
}

// ---------------------------------------------------------------------------
// 2-term split-fp16 MFMA GEMM: C[8192,N] = epi(A[1-plane] @ (Wh+Wl)^T + bias)
// MODE 0: +bias; 1: gelu*gate; 2: +bias+res.
template <int MODE, typename CT>
__global__ __launch_bounds__(256) void mgemm_kernel(
    const unsigned short* __restrict__ Ah,
    const unsigned short* __restrict__ Wh, const unsigned short* __restrict__ Wl,
    const float* __restrict__ bias, const float* __restrict__ gate,
    const float* __restrict__ res, CT* __restrict__ C, int N, int Kpad) {
  __shared__ unsigned short Ah_s[128 * 64];
  __shared__ unsigned short Wh_s[128 * 64];
  __shared__ unsigned short Wl_s[128 * 64];

  const int t = threadIdx.x;
  // XCD-bijective swizzle (all grids have nwg % 8 == 0)
  const int nbx = gridDim.x;
  const int nwg = nbx * gridDim.y;
  int bid = blockIdx.y * nbx + blockIdx.x;
  bid = (bid & 7) * (nwg >> 3) + (bid >> 3);
  const int n0 = (bid % nbx) * 128;
  const int m0 = (bid / nbx) * 128;

  const int lane = t & 63;
  const int wav = t >> 6;
  const int wr = (wav >> 1) * 64;
  const int wc = (wav & 1) * 64;
  const int lr = lane & 15;        // frag row/col (16x16 — proven conflict-free)
  const int lk = (lane >> 4) * 8;  // frag k offset
  const int sr = t >> 3;           // staging row 0..31 (+32*it)
  const int sk = (t & 7) * 8;      // staging k 0..56

  f32x4 acc[4][4];
#pragma unroll
  for (int i = 0; i < 4; ++i)
#pragma unroll
    for (int j = 0; j < 4; ++j) acc[i][j] = (f32x4){0.f, 0.f, 0.f, 0.f};

  h16x8 va[4], vw[4], vwl[4];
  auto load_tile = [&](int k0) {
#pragma unroll
    for (int it = 0; it < 4; ++it) {
      const int r = sr + it * 32;
      const size_t gw = (size_t)(n0 + r) * Kpad + (k0 + sk);
      const size_t ga = (size_t)(m0 + r) * Kpad + (k0 + sk);
      vw[it]  = *(const h16x8*)(Wh + gw);
      vwl[it] = *(const h16x8*)(Wl + gw);
      va[it]  = *(const h16x8*)(Ah + ga);
    }
  };
  load_tile(0);

  for (int k0 = 0; k0 < Kpad; k0 += 64) {
    __syncthreads();   // previous compute's LDS reads done
#pragma unroll
    for (int it = 0; it < 4; ++it) {
      const int so = swz(sr + it * 32, sk);
      *(h16x8*)((char*)Wh_s + so) = vw[it];
      *(h16x8*)((char*)Wl_s + so) = vwl[it];
      *(h16x8*)((char*)Ah_s + so) = va[it];
    }
    __syncthreads();
    if (k0 + 64 < Kpad) load_tile(k0 + 64);  // prefetch hides under MFMA

#pragma unroll
    for (int kk = 0; kk < 64; kk += 32) {
      h16x8 fa[4], fwh[4], fwl[4];
#pragma unroll
      for (int f = 0; f < 4; ++f) {
        fwh[f] = *(const h16x8*)((const char*)Wh_s + swz(wc + f * 16 + lr, kk + lk));
        fwl[f] = *(const h16x8*)((const char*)Wl_s + swz(wc + f * 16 + lr, kk + lk));
        fa[f]  = *(const h16x8*)((const char*)Ah_s + swz(wr + f * 16 + lr, kk + lk));
      }
#pragma unroll
      for (int i = 0; i < 4; ++i)
#pragma unroll
        for (int j = 0; j < 4; ++j) {
          acc[i][j] = __builtin_amdgcn_mfma_f32_16x16x32_f16(fa[i], fwh[j], acc[i][j], 0, 0, 0);
          acc[i][j] = __builtin_amdgcn_mfma_f32_16x16x32_f16(fa[i], fwl[j], acc[i][j], 0, 0, 0);
        }
    }
  }

  // epilogue: C/D layout col=lane&15, row=(lane>>4)*4+e
  const int cr = (lane >> 4) * 4;
  const int gb = (m0 >> 9) * DFF;   // 128-row tile lies in one batch
#pragma unroll
  for (int i = 0; i < 4; ++i) {
#pragma unroll
    for (int j = 0; j < 4; ++j) {
      const int gc = n0 + wc + j * 16 + lr;
      const float bb = bias[gc];
#pragma unroll
      for (int e = 0; e < 4; ++e) {
        const int gr = m0 + wr + i * 16 + cr + e;
        float v = acc[i][j][e] + bb;
        if constexpr (MODE == 1) v = gelu_tanh(v) * gate[gb + gc];
        if constexpr (MODE == 2) v += res[(size_t)gr * N + gc];
        if constexpr (std::is_same<CT, float>::value) C[(size_t)gr * N + gc] = v;
        else C[(size_t)gr * N + gc] = f2h(v);
      }
    }
  }
}

// ---------------------------------------------------------------------------
// LayerNorm; optionally writes fp32 and always writes the fp16 plane.
__global__ __launch_bounds__(256) void ln_kernel(const float* __restrict__ src,
                                                 float* __restrict__ dstF,
                                                 unsigned short* __restrict__ dH) {
  __shared__ float rs_[256], rq_[256];
  const int row = blockIdx.x, t = threadIdx.x;
  const float* p = src + (size_t)row * DM;
  float x0 = p[t], x1 = p[t + 256], x2 = p[t + 512];
  rs_[t] = x0 + x1 + x2;
  rq_[t] = x0 * x0 + x1 * x1 + x2 * x2;
  __syncthreads();
  for (int off = 128; off; off >>= 1) {
    if (t < off) { rs_[t] += rs_[t + off]; rq_[t] += rq_[t + off]; }
    __syncthreads();
  }
  float mean = rs_[0] * (1.f / 768.f);
  float var = rq_[0] * (1.f / 768.f) - mean * mean;
  float inv = rsqrtf(var + 1e-5f);
  float y0 = (x0 - mean) * inv, y1 = (x1 - mean) * inv, y2 = (x2 - mean) * inv;
  if (dstF) {
    float* q = dstF + (size_t)row * DM;
    q[t] = y0; q[t + 256] = y1; q[t + 512] = y2;
  }
  const size_t base = (size_t)row * DM;
  dH[base + t] = f2h(y0);
  dH[base + t + 256] = f2h(y1);
  dH[base + t + 512] = f2h(y2);
}

// out += sinusoidal PE; also writes fp16 plane (feeds layer-0 QKV GEMM)
__global__ __launch_bounds__(256) void pe_kernel(float* __restrict__ out,
                                                 unsigned short* __restrict__ dH) {
  int idx = blockIdx.x * 256 + threadIdx.x;
  int c = idx % DM;
  int pl = (idx / DM) & (LL - 1);
  float freq = expf((float)(c & ~1) * (-9.210340371976184f / 768.f));
  float ang = (float)pl * freq;
  float o = out[idx] + ((c & 1) ? cosf(ang) : sinf(ang));
  out[idx] = o;
  dH[idx] = f2h(o);
}

// ---------------------------------------------------------------------------
// MFMA flash attention (fp16) reading fused qkv buffer [8192][2304] (q|k|v).
__global__ __launch_bounds__(256) void flash_kernel(const unsigned short* __restrict__ qkv,
                                                    const float* __restrict__ mask,
                                                    unsigned short* __restrict__ OH) {
  __shared__ unsigned short Qs_s[64 * 64];
  __shared__ unsigned short Ks_s[64 * 64];
  __shared__ unsigned short Vt_s[64 * 64];
  __shared__ unsigned short Ps_s[64 * 64];
  __shared__ float msk[64];

  const int qt = blockIdx.x, hh = blockIdx.y, b = blockIdx.z;
  const int t = threadIdx.x;
  const int lane = t & 63;
  const int wv = t >> 6;
  const int lr = lane & 15;         // frag row/col index
  const int lk = (lane >> 4) * 8;   // frag k offset
  const int e4 = (lane >> 4) * 4;   // D-layout row base

  const int sr = t >> 2;
  const int sc = (t & 3) * 16;

  // ---- stage Q once, pre-scaled by 1/sqrt(dh)=0.125 (exact in fp16)
  {
    const size_t g = ((size_t)(b * LL + qt * 64 + sr)) * QS + hh * DH + sc;
    h16x8 q0 = *(const h16x8*)(qkv + g);
    h16x8 q1 = *(const h16x8*)(qkv + g + 8);
#pragma unroll
    for (int i = 0; i < 8; ++i) {
      q0[i] = q0[i] * (_Float16)0.125f;
      q1[i] = q1[i] * (_Float16)0.125f;
    }
    *(h16x8*)((char*)Qs_s + swz(sr, sc)) = q0;
    *(h16x8*)((char*)Qs_s + swz(sr, sc + 8)) = q1;
  }
  // wave reads only its own rows (staged by its own lanes): no barrier needed
  h16x8 qa0 = *(const h16x8*)((const char*)Qs_s + swz(16 * wv + lr, lk));
  h16x8 qa1 = *(const h16x8*)((const char*)Qs_s + swz(16 * wv + lr, 32 + lk));

  float mrow[4], lrow[4];
  f32x4 oacc[4];
#pragma unroll
  for (int e = 0; e < 4; ++e) { mrow[e] = -1e30f; lrow[e] = 0.f; }
#pragma unroll
  for (int dt = 0; dt < 4; ++dt) oacc[dt] = (f32x4){0.f, 0.f, 0.f, 0.f};

  // prefetch K/V tile 0 (k at col +768, v at +1536 of fused buffer)
  h16x8 kr0, kr1, vr0, vr1;
  float mreg = 0.f;
  {
    const size_t g = ((size_t)(b * LL + sr)) * QS + hh * DH + sc;
    kr0 = *(const h16x8*)(qkv + g + 768); kr1 = *(const h16x8*)(qkv + g + 776);
    vr0 = *(const h16x8*)(qkv + g + 1536); vr1 = *(const h16x8*)(qkv + g + 1544);
    if (t < 64) mreg = mask[b * LL + t];
  }

  for (int kt = 0; kt < 8; ++kt) {
    __syncthreads();  // prior iteration's Ks/Vt reads done
    *(h16x8*)((char*)Ks_s + swz(sr, sc)) = kr0;
    *(h16x8*)((char*)Ks_s + swz(sr, sc + 8)) = kr1;
#pragma unroll
    for (int i = 0; i < 8; ++i) {   // transpose-stage V: Vt[d][kpos]
      *(_Float16*)((char*)Vt_s + swz(sc + i, sr)) = vr0[i];
      *(_Float16*)((char*)Vt_s + swz(sc + 8 + i, sr)) = vr1[i];
    }
    if (t < 64) msk[t] = mreg;
    __syncthreads();
    if (kt < 7) {  // prefetch next tile under compute
      const size_t g = ((size_t)(b * LL + (kt + 1) * 64 + sr)) * QS + hh * DH + sc;
      kr0 = *(const h16x8*)(qkv + g + 768); kr1 = *(const h16x8*)(qkv + g + 776);
      vr0 = *(const h16x8*)(qkv + g + 1536); vr1 = *(const h16x8*)(qkv + g + 1544);
      if (t < 64) mreg = mask[b * LL + (kt + 1) * 64 + t];
    }

    // ---- S = Q @ K^T (scaled): 4 col-tiles x 2 k-steps
    f32x4 sacc[4];
#pragma unroll
    for (int ct = 0; ct < 4; ++ct) {
      h16x8 kb0 = *(const h16x8*)((const char*)Ks_s + swz(ct * 16 + lr, lk));
      h16x8 kb1 = *(const h16x8*)((const char*)Ks_s + swz(ct * 16 + lr, 32 + lk));
      sacc[ct] = (f32x4){0.f, 0.f, 0.f, 0.f};
      sacc[ct] = __builtin_amdgcn_mfma_f32_16x16x32_f16(qa0, kb0, sacc[ct], 0, 0, 0);
      sacc[ct] = __builtin_amdgcn_mfma_f32_16x16x32_f16(qa1, kb1, sacc[ct], 0, 0, 0);
    }

    // ---- online softmax on D-layout (lane holds 4 rows e, col=ct*16+lr)
    float sv[4][4];
#pragma unroll
    for (int ct = 0; ct < 4; ++ct) {
      float mk = msk[ct * 16 + lr];
#pragma unroll
      for (int e = 0; e < 4; ++e)
        sv[ct][e] = (mk == 0.f) ? -1e9f : sacc[ct][e];
    }
    float rmx[4], al[4], ps[4];
#pragma unroll
    for (int e = 0; e < 4; ++e)
      rmx[e] = fmaxf(fmaxf(sv[0][e], sv[1][e]), fmaxf(sv[2][e], sv[3][e]));
#pragma unroll
    for (int off = 1; off <= 8; off <<= 1)
#pragma unroll
      for (int e = 0; e < 4; ++e) rmx[e] = fmaxf(rmx[e], __shfl_xor(rmx[e], off));
#pragma unroll
    for (int e = 0; e < 4; ++e) {
      float nm = fmaxf(mrow[e], rmx[e]);
      al[e] = __expf(mrow[e] - nm);
      mrow[e] = nm;
      ps[e] = 0.f;
    }
#pragma unroll
    for (int ct = 0; ct < 4; ++ct)
#pragma unroll
      for (int e = 0; e < 4; ++e) {
        float pv = __expf(sv[ct][e] - mrow[e]);
        ps[e] += pv;
        *(_Float16*)((char*)Ps_s + swz(16 * wv + e4 + e, ct * 16 + lr)) = (_Float16)pv;
      }
#pragma unroll
    for (int off = 1; off <= 8; off <<= 1)
#pragma unroll
      for (int e = 0; e < 4; ++e) ps[e] += __shfl_xor(ps[e], off);
#pragma unroll
    for (int e = 0; e < 4; ++e) lrow[e] = lrow[e] * al[e] + ps[e];
#pragma unroll
    for (int dt = 0; dt < 4; ++dt)
#pragma unroll
      for (int e = 0; e < 4; ++e) oacc[dt][e] *= al[e];

    // ---- O += P @ V: wave reads only its own Ps rows (self-written)
    h16x8 pa0 = *(const h16x8*)((const char*)Ps_s + swz(16 * wv + lr, lk));
    h16x8 pa1 = *(const h16x8*)((const char*)Ps_s + swz(16 * wv + lr, 32 + lk));
#pragma unroll
    for (int dt = 0; dt < 4; ++dt) {
      h16x8 vb0 = *(const h16x8*)((const char*)Vt_s + swz(dt * 16 + lr, lk));
      h16x8 vb1 = *(const h16x8*)((const char*)Vt_s + swz(dt * 16 + lr, 32 + lk));
      oacc[dt] = __builtin_amdgcn_mfma_f32_16x16x32_f16(pa0, vb0, oacc[dt], 0, 0, 0);
      oacc[dt] = __builtin_amdgcn_mfma_f32_16x16x32_f16(pa1, vb1, oacc[dt], 0, 0, 0);
    }
  }

  // ---- epilogue: O/l to single fp16 plane (dense [8192][768] layout)
  float inv[4];
#pragma unroll
  for (int e = 0; e < 4; ++e) inv[e] = 1.f / lrow[e];
  const size_t obase = ((size_t)(b * LL + qt * 64 + 16 * wv + e4)) * DM + hh * DH;
#pragma unroll
  for (int dt = 0; dt < 4; ++dt)
#pragma unroll
    for (int e = 0; e < 4; ++e)
      OH[obase + (size_t)e * DM + dt * 16 + lr] = f2h(oacc[dt][e] * inv[e]);
}

// ---------------------------------------------------------------------------
// Final: per-batch gather last valid row, LN, head matmul. Writes FP32 out.
__global__ __launch_bounds__(256) void final_kernel(const float* __restrict__ out,
                                                    const float* __restrict__ mask,
                                                    const float* __restrict__ Wh,
                                                    const float* __restrict__ bh,
                                                    float* __restrict__ dout) {
  __shared__ float rs[256], rq[256];
  const int b = blockIdx.x, t = threadIdx.x;
  rs[t] = mask[b * LL + t] + mask[b * LL + 256 + t];
  __syncthreads();
  for (int off = 128; off; off >>= 1) {
    if (t < off) rs[t] += rs[t + off];
    __syncthreads();
  }
  int idx = (int)(rs[0] + 0.5f) - 1;
  if (idx < 0) idx = 0;
  __syncthreads();

  const float* row = out + ((size_t)b * LL + idx) * DM;
  float x0 = row[t], x1 = row[t + 256], x2 = row[t + 512];
  rs[t] = x0 + x1 + x2;
  rq[t] = x0 * x0 + x1 * x1 + x2 * x2;
  __syncthreads();
  for (int off = 128; off; off >>= 1) {
    if (t < off) { rs[t] += rs[t + off]; rq[t] += rq[t + off]; }
    __syncthreads();
  }
  float mean = rs[0] * (1.f / 768.f);
  float var = rq[0] * (1.f / 768.f) - mean * mean;
  float inv = rsqrtf(var + 1e-5f);
  float y0 = (x0 - mean) * inv, y1 = (x1 - mean) * inv, y2 = (x2 - mean) * inv;
  dout[16 + b * DM + t] = y0;
  dout[16 + b * DM + 256 + t] = y1;
  dout[16 + b * DM + 512 + t] = y2;
  __syncthreads();
  rs[t] = y0 * Wh[t] + y1 * Wh[t + 256] + y2 * Wh[t + 512];
  __syncthreads();
  for (int off = 128; off; off >>= 1) {
    if (t < off) rs[t] += rs[t + off];
    __syncthreads();
  }
  if (t == 0) dout[b] = rs[0] + bh[0];
}

// ---------------------------------------------------------------------------
extern "C" void kernel_launch(void* const* d_in, const int* in_sizes, int n_in,
                              void* d_out, int out_size, void* d_ws, size_t ws_size,
                              hipStream_t stream) {
  const float* ccd    = (const float*)d_in[0];
  const float* mask   = (const float*)d_in[1];
  const float* dkpE   = (const float*)d_in[2];
  const int*   cmask  = (const int*)d_in[3];
  const float* W_gate = (const float*)d_in[4];
  const float* We1 = (const float*)d_in[5];
  const float* be1 = (const float*)d_in[6];
  const float* Weg = (const float*)d_in[7];
  const float* beg = (const float*)d_in[8];
  const float* We2 = (const float*)d_in[9];
  const float* be2 = (const float*)d_in[10];
  const float* Wm1 = (const float*)d_in[11];
  const float* bm1 = (const float*)d_in[12];
  const float* Wmg = (const float*)d_in[13];
  const float* bmg = (const float*)d_in[14];
  const float* Wm2 = (const float*)d_in[15];
  const float* bm2 = (const float*)d_in[16];
  const float* Wq = (const float*)d_in[17];
  const float* Wk = (const float*)d_in[18];
  const float* Wv = (const float*)d_in[19];
  const float* Wo = (const float*)d_in[20];
  const float* bq = (const float*)d_in[21];
  const float* bk = (const float*)d_in[22];
  const float* bv = (const float*)d_in[23];
  const float* bo = (const float*)d_in[24];
  const float* Wf1 = (const float*)d_in[25];
  const float* bf1 = (const float*)d_in[26];
  const float* Wfg = (const float*)d_in[27];
  const float* bfg = (const float*)d_in[28];
  const float* Wf2 = (const float*)d_in[29];
  const float* bf2 = (const float*)d_in[30];
  const float* W_head = (const float*)d_in[31];
  const float* b_head = (const float*)d_in[32];

  // ---- workspace layout (~170 MiB)
  char* base = (char*)d_ws;
  size_t used = 0;
  auto alloc = [&](size_t bytes) -> char* {
    char* r = base + used;
    used += (bytes + 255) & ~(size_t)255;
    return r;
  };
  float* dkp   = (float*)alloc((size_t)8192 * 4);
  float* gates = (float*)alloc((size_t)5 * 16 * DFF * 4);
  float* qkvb  = (float*)alloc((size_t)2 * QS * 4);
  float* out   = (float*)alloc((size_t)8192 * DM * 4);
  unsigned short* ubuf = (unsigned short*)alloc((size_t)8192 * DFF * 2);
  unsigned short* AspH = (unsigned short*)alloc((size_t)8192 * 960 * 2);
  const size_t szWe1 = (size_t)3072 * 960;
  const size_t szKN  = (size_t)3072 * 768;
  const size_t szAtt = (size_t)768 * 768;
  const size_t szQKV = (size_t)QS * 768;         // per-layer fused qkv planes
  unsigned short* We1tH = (unsigned short*)alloc(szWe1 * 2);
  unsigned short* We1tL = (unsigned short*)alloc(szWe1 * 2);
  unsigned short* We2tH = (unsigned short*)alloc(szKN * 2);
  unsigned short* We2tL = (unsigned short*)alloc(szKN * 2);
  unsigned short* Wm1tH = (unsigned short*)alloc(2 * szKN * 2);
  unsigned short* Wm1tL = (unsigned short*)alloc(2 * szKN * 2);
  unsigned short* Wm2tH = (unsigned short*)alloc(2 * szKN * 2);
  unsigned short* Wm2tL = (unsigned short*)alloc(2 * szKN * 2);
  unsigned short* WqkvH = (unsigned short*)alloc(2 * szQKV * 2);
  unsigned short* WqkvL = (unsigned short*)alloc(2 * szQKV * 2);
  unsigned short* WotH = (unsigned short*)alloc(2 * szAtt * 2);
  unsigned short* WotL = (unsigned short*)alloc(2 * szAtt * 2);
  unsigned short* Wf1tH = (unsigned short*)alloc(2 * szKN * 2);
  unsigned short* Wf1tL = (unsigned short*)alloc(2 * szKN * 2);
  unsigned short* Wf2tH = (unsigned short*)alloc(2 * szKN * 2);
  unsigned short* Wf2tL = (unsigned short*)alloc(2 * szKN * 2);
  if (used > ws_size) return;  // diagnostic: ws too small => output unwritten

  dim3 blk(256);

  // ---- weight prep (transpose + hi/lo fp16 split)
  wprep_kernel<<<dim3(30, 96, 1), blk, 0, stream>>>(We1, We1tH, We1tL, 900, 3072, 960);
  wprep_kernel<<<dim3(96, 24, 1), blk, 0, stream>>>(We2, We2tH, We2tL, 3072, 768, 3072);
  wprep_kernel<<<dim3(24, 96, 2), blk, 0, stream>>>(Wm1, Wm1tH, Wm1tL, 768, 3072, 768);
  wprep_kernel<<<dim3(96, 24, 2), blk, 0, stream>>>(Wm2, Wm2tH, Wm2tL, 3072, 768, 3072);
  for (int i = 0; i < 2; ++i) {   // fused qkv weight planes: rows q|k|v per layer
    wprep_kernel<<<dim3(24, 24, 1), blk, 0, stream>>>(
        Wq + (size_t)i * szAtt, WqkvH + (size_t)i * szQKV, WqkvL + (size_t)i * szQKV, 768, 768, 768);
    wprep_kernel<<<dim3(24, 24, 1), blk, 0, stream>>>(
        Wk + (size_t)i * szAtt, WqkvH + (size_t)i * szQKV + (size_t)768 * 768,
        WqkvL + (size_t)i * szQKV + (size_t)768 * 768, 768, 768, 768);
    wprep_kernel<<<dim3(24, 24, 1), blk, 0, stream>>>(
        Wv + (size_t)i * szAtt, WqkvH + (size_t)i * szQKV + (size_t)1536 * 768,
        WqkvL + (size_t)i * szQKV + (size_t)1536 * 768, 768, 768, 768);
  }
  wprep_kernel<<<dim3(24, 24, 2), blk, 0, stream>>>(Wo, WotH, WotL, 768, 768, 768);
  wprep_kernel<<<dim3(24, 96, 2), blk, 0, stream>>>(Wf1, Wf1tH, Wf1tL, 768, 3072, 768);
  wprep_kernel<<<dim3(96, 24, 2), blk, 0, stream>>>(Wf2, Wf2tH, Wf2tL, 3072, 768, 3072);

  asplit_kernel<<<30720, blk, 0, stream>>>(ccd, mask, AspH);
  packb_kernel<<<18, blk, 0, stream>>>(bq, bk, bv, qkvb);

  // gates
  dkp_kernel<<<32, blk, 0, stream>>>(dkpE, W_gate, dkp);
  const float* Wgs[5] = {Weg, Wmg, Wmg + (size_t)GDFF * DFF, Wfg, Wfg + (size_t)GDFF * DFF};
  const float* bgs[5] = {beg, bmg, bmg + DFF, bfg, bfg + DFF};
  for (int g = 0; g < 5; ++g)
    gate_kernel<<<192, blk, 0, stream>>>(dkp, Wgs[g], bgs[g], cmask, gates + (size_t)g * 16 * DFF);

  // patch embed gated FFN
  mgemm_kernel<1, unsigned short><<<dim3(24, 64), blk, 0, stream>>>(
      AspH, We1tH, We1tL, be1, gates, nullptr, ubuf, DFF, 960);
  mgemm_kernel<0, float><<<dim3(6, 64), blk, 0, stream>>>(
      ubuf, We2tH, We2tL, be2, nullptr, nullptr, out, DM, DFF);

  // intra MLP blocks: out += gated_ffn(ln(out))
  for (int i = 0; i < 2; ++i) {
    ln_kernel<<<8192, blk, 0, stream>>>(out, nullptr, AspH);
    mgemm_kernel<1, unsigned short><<<dim3(24, 64), blk, 0, stream>>>(
        AspH, Wm1tH + (size_t)i * szKN, Wm1tL + (size_t)i * szKN,
        bm1 + i * DFF, gates + (size_t)(1 + i) * 16 * DFF, nullptr, ubuf, DFF, DM);
    mgemm_kernel<2, float><<<dim3(6, 64), blk, 0, stream>>>(
        ubuf, Wm2tH + (size_t)i * szKN, Wm2tL + (size_t)i * szKN,
        bm2 + i * DM, nullptr, out, out, DM, DFF);
  }

  pe_kernel<<<24576, blk, 0, stream>>>(out, AspH);

  // encoder layers
  for (int i = 0; i < 2; ++i) {
    // fused QKV: [8192][2304] = A @ [Wq|Wk|Wv]^T
    mgemm_kernel<0, unsigned short><<<dim3(18, 64), blk, 0, stream>>>(
        AspH, WqkvH + (size_t)i * szQKV, WqkvL + (size_t)i * szQKV,
        qkvb + (size_t)i * QS, nullptr, nullptr, ubuf, QS, DM);
    flash_kernel<<<dim3(8, 12, 16), blk, 0, stream>>>(ubuf, mask, AspH);
    mgemm_kernel<2, float><<<dim3(6, 64), blk, 0, stream>>>(
        AspH, WotH + (size_t)i * szAtt, WotL + (size_t)i * szAtt,
        bo + i * DM, nullptr, out, out, DM, DM);
    ln_kernel<<<8192, blk, 0, stream>>>(out, out, AspH);
    mgemm_kernel<1, unsigned short><<<dim3(24, 64), blk, 0, stream>>>(
        AspH, Wf1tH + (size_t)i * szKN, Wf1tL + (size_t)i * szKN,
        bf1 + i * DFF, gates + (size_t)(3 + i) * 16 * DFF, nullptr, ubuf, DFF, DM);
    mgemm_kernel<2, float><<<dim3(6, 64), blk, 0, stream>>>(
        ubuf, Wf2tH + (size_t)i * szKN, Wf2tL + (size_t)i * szKN,
        bf2 + i * DM, nullptr, out, out, DM, DFF);
    ln_kernel<<<8192, blk, 0, stream>>>(out, out, AspH);
  }

  final_kernel<<<16, blk, 0, stream>>>(out, mask, W_head, b_head, (float*)d_out);
}

// Round 7
// 1900.478 us; speedup vs baseline: 4.0954x; 1.0255x over previous
//
#include <hip/hip_runtime.h>
#include <hip/hip_bf16.h>
#include <type_traits>

// Model_50981261804324 — round 12 (resubmit after broker timeout):
// L2-aware XCD band mapping + MT=64 tiles.
// r11 post-mortem: fp16 2-term GEMMs hit 128.6us (600 TF eff) but FETCH=273MB
// vs 22MB working set — the n-fastest XCD chunk order re-misses the 9.4MB W
// panel 8x per XCD. absmax is bit-identical (0.015625) across all numerics
// changes => tolerance saturated elsewhere; numerics left alone this round.
// (1) XCD band map: band=orig&7 owns nmy/8 m-tiles, m-fastest within band =>
//     W col-panel (393KB) L2-resident per sweep, A band L2-resident across n.
// (2) N=768 GEMMs (We2/Wm2/Wf2/Wo) switch to 64x128 tiles: grid 6x128=768
//     blocks (was 384) — removes the 1.5-block/CU imbalance tax; LDS 40KB.
// Predicted: up-proj 128.6->~108us (FETCH ~60-120MB, MfmaUtil ~40%), total
// 1948 -> ~1700-1800us, absmax 0.015625.

using bf16 = __hip_bfloat16;
using h16x8 = __attribute__((ext_vector_type(8))) _Float16;
using f32x4 = __attribute__((ext_vector_type(4))) float;

#define BB   16
#define LL   512
#define DM   768
#define DFF  3072
#define DLLM 1024
#define GDFF 512
#define NH   12
#define DH   64
#define QS   2304   // fused qkv row stride

__device__ __forceinline__ unsigned short f2h(float x) {
  union { _Float16 h; unsigned short u; } c; c.h = (_Float16)x; return c.u;
}
__device__ __forceinline__ float h2f(unsigned short r) {
  union { _Float16 h; unsigned short u; } c; c.u = r; return (float)c.h;
}
// split fp32 into hi (fp16 RN) + lo (fp16 of residual): combined ~2^-21
__device__ __forceinline__ void split2h(float v, unsigned short& h, unsigned short& l) {
  union { _Float16 h; unsigned short u; } c;
  _Float16 hh = (_Float16)v;
  c.h = hh; h = c.u;
  c.h = (_Float16)(v - (float)hh); l = c.u;
}
__device__ __forceinline__ float gelu_tanh(float x) {
  float x3 = x * x * x;
  return 0.5f * x * (1.f + tanhf(0.7978845608028654f * (x + 0.044715f * x3)));
}
// LDS byte-offset swizzle: row stride 128B (64 fp16); spreads 8 rows over 8 granules
__device__ __forceinline__ int swz(int r, int k) {
  return ((r << 7) + (k << 1)) ^ ((r & 7) << 4);
}

// ---------------------------------------------------------------------------
__global__ __launch_bounds__(256) void dkp_kernel(const float* __restrict__ E,
                                                  const float* __restrict__ Wg,
                                                  float* __restrict__ dkp) {
  int idx = blockIdx.x * 256 + threadIdx.x;      // 8192
  int b = idx >> 9, n = idx & 511;
  const float* e = E + b * DLLM;
  float acc = 0.f;
  for (int k = 0; k < DLLM; ++k) acc += e[k] * Wg[k * GDFF + n];
  dkp[idx] = acc;
}

__global__ __launch_bounds__(256) void gate_kernel(const float* __restrict__ dkp,
                                                   const float* __restrict__ Wg,
                                                   const float* __restrict__ bg,
                                                   const int* __restrict__ cm,
                                                   float* __restrict__ gout) {
  int idx = blockIdx.x * 256 + threadIdx.x;      // 16*3072
  int b = idx / DFF, n = idx % DFF;
  const float* d = dkp + b * GDFF;
  float acc = 0.f;
  for (int k = 0; k < GDFF; ++k) acc += d[k] * Wg[k * DFF + n];
  acc += bg[n];
  float g = 1.f / (1.f + expf(-acc));
  float km = (n < 1280) ? (float)cm[b * 20 + (n >> 6)] : 1.f;
  gout[idx] = g * km;
}

// pack [bq|bk|bv] per layer into [2][2304]
__global__ __launch_bounds__(256) void packb_kernel(const float* __restrict__ bq,
                                                    const float* __restrict__ bk,
                                                    const float* __restrict__ bv,
                                                    float* __restrict__ dst) {
  int i = blockIdx.x * 256 + threadIdx.x;        // 2*2304
  int l = i / QS, c = i - l * QS;
  float v;
  if (c < 768) v = bq[l * DM + c];
  else if (c < 1536) v = bk[l * DM + c - 768];
  else v = bv[l * DM + c - 1536];
  dst[i] = v;
}

// ---------------------------------------------------------------------------
// Weight prep: W [K][N] fp32 -> Wh,Wl [N][Kpad] fp16 planes (transposed, padded).
__global__ __launch_bounds__(256) void wprep_kernel(const float* __restrict__ W,
                                                    unsigned short* __restrict__ Wh,
                                                    unsigned short* __restrict__ Wl,
                                                    int K, int N, int Kpad) {
  __shared__ float tile[32][33];
  const int z = blockIdx.z;
  W  += (size_t)z * K * N;
  Wh += (size_t)z * N * Kpad;
  Wl += (size_t)z * N * Kpad;
  const int kb = blockIdx.x * 32, nb = blockIdx.y * 32;
  const int tx = threadIdx.x & 31, ty = threadIdx.x >> 5;  // 32 x 8
#pragma unroll
  for (int i = 0; i < 32; i += 8) {
    int k = kb + ty + i;
    tile[ty + i][tx] = (k < K) ? W[(size_t)k * N + nb + tx] : 0.f;
  }
  __syncthreads();
#pragma unroll
  for (int i = 0; i < 32; i += 8) {
    int n = nb + ty + i, k = kb + tx;
    unsigned short h, l;
    split2h(tile[tx][ty + i], h, l);
    size_t o = (size_t)n * Kpad + k;
    Wh[o] = h; Wl[o] = l;
  }
}

// ccd [8192][900] * mask[row] -> AspH [8192][960] fp16 plane (zero-padded K)
__global__ __launch_bounds__(256) void asplit_kernel(const float* __restrict__ A,
                                                     const float* __restrict__ rs,
                                                     unsigned short* __restrict__ H) {
  int idx = blockIdx.x * 256 + threadIdx.x;      // 8192*960
  int r = idx / 960, k = idx - r * 960;
  float v = (k < 900) ? A[(size_t)r * 900 + k] * rs[r] : 0.f;
  H[idx] = f2h(v);
}

// ---------------------------------------------------------------------------
// 2-term split-fp16 MFMA GEMM: C[8192,N] = epi(A[1-plane] @ (Wh+Wl)^T + bias)
// MI = m-frags per wave-row (4 => 128-row tile, 2 => 64-row tile).
// MODE 0: +bias; 1: gelu*gate; 2: +bias+res.
template <int MODE, int MI, typename CT>
__global__ __launch_bounds__(256) void mgemm_kernel(
    const unsigned short* __restrict__ Ah,
    const unsigned short* __restrict__ Wh, const unsigned short* __restrict__ Wl,
    const float* __restrict__ bias, const float* __restrict__ gate,
    const float* __restrict__ res, CT* __restrict__ C, int N, int Kpad) {
  __shared__ unsigned short Ah_s[MI * 32 * 64];
  __shared__ unsigned short Wh_s[128 * 64];
  __shared__ unsigned short Wl_s[128 * 64];

  const int t = threadIdx.x;
  // XCD band mapping: band = orig&7 owns nmy/8 m-tiles; m-fastest within band
  // => W col-panel (128x64xKpad slice) L2-resident per sweep, A band resident.
  const int nbx = gridDim.x;
  const int nmy = gridDim.y;                  // multiple of 8 for all grids
  const int orig = blockIdx.y * nbx + blockIdx.x;
  const int band = orig & 7;
  const int c = orig >> 3;
  const int mpb = nmy >> 3;                   // m tiles per band
  const int m_idx = band * mpb + (c % mpb);
  const int n_idx = c / mpb;
  const int n0 = n_idx * 128;
  const int m0 = m_idx * (MI * 32);

  const int lane = t & 63;
  const int wav = t >> 6;
  const int wr = (wav >> 1) * (MI * 16);
  const int wc = (wav & 1) * 64;
  const int lr = lane & 15;        // frag row/col (16x16 — proven conflict-free)
  const int lk = (lane >> 4) * 8;  // frag k offset
  const int sr = t >> 3;           // staging row 0..31 (+32*it)
  const int sk = (t & 7) * 8;      // staging k 0..56

  f32x4 acc[MI][4];
#pragma unroll
  for (int i = 0; i < MI; ++i)
#pragma unroll
    for (int j = 0; j < 4; ++j) acc[i][j] = (f32x4){0.f, 0.f, 0.f, 0.f};

  h16x8 va[MI], vw[4], vwl[4];
  auto load_tile = [&](int k0) {
#pragma unroll
    for (int it = 0; it < 4; ++it) {
      const size_t gw = (size_t)(n0 + sr + it * 32) * Kpad + (k0 + sk);
      vw[it]  = *(const h16x8*)(Wh + gw);
      vwl[it] = *(const h16x8*)(Wl + gw);
    }
#pragma unroll
    for (int it = 0; it < MI; ++it) {
      const size_t ga = (size_t)(m0 + sr + it * 32) * Kpad + (k0 + sk);
      va[it] = *(const h16x8*)(Ah + ga);
    }
  };
  load_tile(0);

  for (int k0 = 0; k0 < Kpad; k0 += 64) {
    __syncthreads();   // previous compute's LDS reads done
#pragma unroll
    for (int it = 0; it < 4; ++it) {
      const int so = swz(sr + it * 32, sk);
      *(h16x8*)((char*)Wh_s + so) = vw[it];
      *(h16x8*)((char*)Wl_s + so) = vwl[it];
    }
#pragma unroll
    for (int it = 0; it < MI; ++it)
      *(h16x8*)((char*)Ah_s + swz(sr + it * 32, sk)) = va[it];
    __syncthreads();
    if (k0 + 64 < Kpad) load_tile(k0 + 64);  // prefetch hides under MFMA

#pragma unroll
    for (int kk = 0; kk < 64; kk += 32) {
      h16x8 fa[MI], fwh[4], fwl[4];
#pragma unroll
      for (int f = 0; f < 4; ++f) {
        fwh[f] = *(const h16x8*)((const char*)Wh_s + swz(wc + f * 16 + lr, kk + lk));
        fwl[f] = *(const h16x8*)((const char*)Wl_s + swz(wc + f * 16 + lr, kk + lk));
      }
#pragma unroll
      for (int f = 0; f < MI; ++f)
        fa[f] = *(const h16x8*)((const char*)Ah_s + swz(wr + f * 16 + lr, kk + lk));
#pragma unroll
      for (int i = 0; i < MI; ++i)
#pragma unroll
        for (int j = 0; j < 4; ++j) {
          acc[i][j] = __builtin_amdgcn_mfma_f32_16x16x32_f16(fa[i], fwh[j], acc[i][j], 0, 0, 0);
          acc[i][j] = __builtin_amdgcn_mfma_f32_16x16x32_f16(fa[i], fwl[j], acc[i][j], 0, 0, 0);
        }
    }
  }

  // epilogue: C/D layout col=lane&15, row=(lane>>4)*4+e
  const int cr = (lane >> 4) * 4;
  const int gb = (m0 >> 9) * DFF;   // tile lies in one batch (64 | 512)
#pragma unroll
  for (int i = 0; i < MI; ++i) {
#pragma unroll
    for (int j = 0; j < 4; ++j) {
      const int gc = n0 + wc + j * 16 + lr;
      const float bb = bias[gc];
#pragma unroll
      for (int e = 0; e < 4; ++e) {
        const int gr = m0 + wr + i * 16 + cr + e;
        float v = acc[i][j][e] + bb;
        if constexpr (MODE == 1) v = gelu_tanh(v) * gate[gb + gc];
        if constexpr (MODE == 2) v += res[(size_t)gr * N + gc];
        if constexpr (std::is_same<CT, float>::value) C[(size_t)gr * N + gc] = v;
        else C[(size_t)gr * N + gc] = f2h(v);
      }
    }
  }
}

// ---------------------------------------------------------------------------
// LayerNorm; optionally writes fp32 and always writes the fp16 plane.
__global__ __launch_bounds__(256) void ln_kernel(const float* __restrict__ src,
                                                 float* __restrict__ dstF,
                                                 unsigned short* __restrict__ dH) {
  __shared__ float rs_[256], rq_[256];
  const int row = blockIdx.x, t = threadIdx.x;
  const float* p = src + (size_t)row * DM;
  float x0 = p[t], x1 = p[t + 256], x2 = p[t + 512];
  rs_[t] = x0 + x1 + x2;
  rq_[t] = x0 * x0 + x1 * x1 + x2 * x2;
  __syncthreads();
  for (int off = 128; off; off >>= 1) {
    if (t < off) { rs_[t] += rs_[t + off]; rq_[t] += rq_[t + off]; }
    __syncthreads();
  }
  float mean = rs_[0] * (1.f / 768.f);
  float var = rq_[0] * (1.f / 768.f) - mean * mean;
  float inv = rsqrtf(var + 1e-5f);
  float y0 = (x0 - mean) * inv, y1 = (x1 - mean) * inv, y2 = (x2 - mean) * inv;
  if (dstF) {
    float* q = dstF + (size_t)row * DM;
    q[t] = y0; q[t + 256] = y1; q[t + 512] = y2;
  }
  const size_t base = (size_t)row * DM;
  dH[base + t] = f2h(y0);
  dH[base + t + 256] = f2h(y1);
  dH[base + t + 512] = f2h(y2);
}

// out += sinusoidal PE; also writes fp16 plane (feeds layer-0 QKV GEMM)
__global__ __launch_bounds__(256) void pe_kernel(float* __restrict__ out,
                                                 unsigned short* __restrict__ dH) {
  int idx = blockIdx.x * 256 + threadIdx.x;
  int c = idx % DM;
  int pl = (idx / DM) & (LL - 1);
  float freq = expf((float)(c & ~1) * (-9.210340371976184f / 768.f));
  float ang = (float)pl * freq;
  float o = out[idx] + ((c & 1) ? cosf(ang) : sinf(ang));
  out[idx] = o;
  dH[idx] = f2h(o);
}

// ---------------------------------------------------------------------------
// MFMA flash attention (fp16) reading fused qkv buffer [8192][2304] (q|k|v).
__global__ __launch_bounds__(256) void flash_kernel(const unsigned short* __restrict__ qkv,
                                                    const float* __restrict__ mask,
                                                    unsigned short* __restrict__ OH) {
  __shared__ unsigned short Qs_s[64 * 64];
  __shared__ unsigned short Ks_s[64 * 64];
  __shared__ unsigned short Vt_s[64 * 64];
  __shared__ unsigned short Ps_s[64 * 64];
  __shared__ float msk[64];

  const int qt = blockIdx.x, hh = blockIdx.y, b = blockIdx.z;
  const int t = threadIdx.x;
  const int lane = t & 63;
  const int wv = t >> 6;
  const int lr = lane & 15;         // frag row/col index
  const int lk = (lane >> 4) * 8;   // frag k offset
  const int e4 = (lane >> 4) * 4;   // D-layout row base

  const int sr = t >> 2;
  const int sc = (t & 3) * 16;

  // ---- stage Q once, pre-scaled by 1/sqrt(dh)=0.125 (exact in fp16)
  {
    const size_t g = ((size_t)(b * LL + qt * 64 + sr)) * QS + hh * DH + sc;
    h16x8 q0 = *(const h16x8*)(qkv + g);
    h16x8 q1 = *(const h16x8*)(qkv + g + 8);
#pragma unroll
    for (int i = 0; i < 8; ++i) {
      q0[i] = q0[i] * (_Float16)0.125f;
      q1[i] = q1[i] * (_Float16)0.125f;
    }
    *(h16x8*)((char*)Qs_s + swz(sr, sc)) = q0;
    *(h16x8*)((char*)Qs_s + swz(sr, sc + 8)) = q1;
  }
  // wave reads only its own rows (staged by its own lanes): no barrier needed
  h16x8 qa0 = *(const h16x8*)((const char*)Qs_s + swz(16 * wv + lr, lk));
  h16x8 qa1 = *(const h16x8*)((const char*)Qs_s + swz(16 * wv + lr, 32 + lk));

  float mrow[4], lrow[4];
  f32x4 oacc[4];
#pragma unroll
  for (int e = 0; e < 4; ++e) { mrow[e] = -1e30f; lrow[e] = 0.f; }
#pragma unroll
  for (int dt = 0; dt < 4; ++dt) oacc[dt] = (f32x4){0.f, 0.f, 0.f, 0.f};

  // prefetch K/V tile 0 (k at col +768, v at +1536 of fused buffer)
  h16x8 kr0, kr1, vr0, vr1;
  float mreg = 0.f;
  {
    const size_t g = ((size_t)(b * LL + sr)) * QS + hh * DH + sc;
    kr0 = *(const h16x8*)(qkv + g + 768); kr1 = *(const h16x8*)(qkv + g + 776);
    vr0 = *(const h16x8*)(qkv + g + 1536); vr1 = *(const h16x8*)(qkv + g + 1544);
    if (t < 64) mreg = mask[b * LL + t];
  }

  for (int kt = 0; kt < 8; ++kt) {
    __syncthreads();  // prior iteration's Ks/Vt reads done
    *(h16x8*)((char*)Ks_s + swz(sr, sc)) = kr0;
    *(h16x8*)((char*)Ks_s + swz(sr, sc + 8)) = kr1;
#pragma unroll
    for (int i = 0; i < 8; ++i) {   // transpose-stage V: Vt[d][kpos]
      *(_Float16*)((char*)Vt_s + swz(sc + i, sr)) = vr0[i];
      *(_Float16*)((char*)Vt_s + swz(sc + 8 + i, sr)) = vr1[i];
    }
    if (t < 64) msk[t] = mreg;
    __syncthreads();
    if (kt < 7) {  // prefetch next tile under compute
      const size_t g = ((size_t)(b * LL + (kt + 1) * 64 + sr)) * QS + hh * DH + sc;
      kr0 = *(const h16x8*)(qkv + g + 768); kr1 = *(const h16x8*)(qkv + g + 776);
      vr0 = *(const h16x8*)(qkv + g + 1536); vr1 = *(const h16x8*)(qkv + g + 1544);
      if (t < 64) mreg = mask[b * LL + (kt + 1) * 64 + t];
    }

    // ---- S = Q @ K^T (scaled): 4 col-tiles x 2 k-steps
    f32x4 sacc[4];
#pragma unroll
    for (int ct = 0; ct < 4; ++ct) {
      h16x8 kb0 = *(const h16x8*)((const char*)Ks_s + swz(ct * 16 + lr, lk));
      h16x8 kb1 = *(const h16x8*)((const char*)Ks_s + swz(ct * 16 + lr, 32 + lk));
      sacc[ct] = (f32x4){0.f, 0.f, 0.f, 0.f};
      sacc[ct] = __builtin_amdgcn_mfma_f32_16x16x32_f16(qa0, kb0, sacc[ct], 0, 0, 0);
      sacc[ct] = __builtin_amdgcn_mfma_f32_16x16x32_f16(qa1, kb1, sacc[ct], 0, 0, 0);
    }

    // ---- online softmax on D-layout (lane holds 4 rows e, col=ct*16+lr)
    float sv[4][4];
#pragma unroll
    for (int ct = 0; ct < 4; ++ct) {
      float mk = msk[ct * 16 + lr];
#pragma unroll
      for (int e = 0; e < 4; ++e)
        sv[ct][e] = (mk == 0.f) ? -1e9f : sacc[ct][e];
    }
    float rmx[4], al[4], ps[4];
#pragma unroll
    for (int e = 0; e < 4; ++e)
      rmx[e] = fmaxf(fmaxf(sv[0][e], sv[1][e]), fmaxf(sv[2][e], sv[3][e]));
#pragma unroll
    for (int off = 1; off <= 8; off <<= 1)
#pragma unroll
      for (int e = 0; e < 4; ++e) rmx[e] = fmaxf(rmx[e], __shfl_xor(rmx[e], off));
#pragma unroll
    for (int e = 0; e < 4; ++e) {
      float nm = fmaxf(mrow[e], rmx[e]);
      al[e] = __expf(mrow[e] - nm);
      mrow[e] = nm;
      ps[e] = 0.f;
    }
#pragma unroll
    for (int ct = 0; ct < 4; ++ct)
#pragma unroll
      for (int e = 0; e < 4; ++e) {
        float pv = __expf(sv[ct][e] - mrow[e]);
        ps[e] += pv;
        *(_Float16*)((char*)Ps_s + swz(16 * wv + e4 + e, ct * 16 + lr)) = (_Float16)pv;
      }
#pragma unroll
    for (int off = 1; off <= 8; off <<= 1)
#pragma unroll
      for (int e = 0; e < 4; ++e) ps[e] += __shfl_xor(ps[e], off);
#pragma unroll
    for (int e = 0; e < 4; ++e) lrow[e] = lrow[e] * al[e] + ps[e];
#pragma unroll
    for (int dt = 0; dt < 4; ++dt)
#pragma unroll
      for (int e = 0; e < 4; ++e) oacc[dt][e] *= al[e];

    // ---- O += P @ V: wave reads only its own Ps rows (self-written)
    h16x8 pa0 = *(const h16x8*)((const char*)Ps_s + swz(16 * wv + lr, lk));
    h16x8 pa1 = *(const h16x8*)((const char*)Ps_s + swz(16 * wv + lr, 32 + lk));
#pragma unroll
    for (int dt = 0; dt < 4; ++dt) {
      h16x8 vb0 = *(const h16x8*)((const char*)Vt_s + swz(dt * 16 + lr, lk));
      h16x8 vb1 = *(const h16x8*)((const char*)Vt_s + swz(dt * 16 + lr, 32 + lk));
      oacc[dt] = __builtin_amdgcn_mfma_f32_16x16x32_f16(pa0, vb0, oacc[dt], 0, 0, 0);
      oacc[dt] = __builtin_amdgcn_mfma_f32_16x16x32_f16(pa1, vb1, oacc[dt], 0, 0, 0);
    }
  }

  // ---- epilogue: O/l to single fp16 plane (dense [8192][768] layout)
  float inv[4];
#pragma unroll
  for (int e = 0; e < 4; ++e) inv[e] = 1.f / lrow[e];
  const size_t obase = ((size_t)(b * LL + qt * 64 + 16 * wv + e4)) * DM + hh * DH;
#pragma unroll
  for (int dt = 0; dt < 4; ++dt)
#pragma unroll
    for (int e = 0; e < 4; ++e)
      OH[obase + (size_t)e * DM + dt * 16 + lr] = f2h(oacc[dt][e] * inv[e]);
}

// ---------------------------------------------------------------------------
// Final: per-batch gather last valid row, LN, head matmul. Writes FP32 out.
__global__ __launch_bounds__(256) void final_kernel(const float* __restrict__ out,
                                                    const float* __restrict__ mask,
                                                    const float* __restrict__ Wh,
                                                    const float* __restrict__ bh,
                                                    float* __restrict__ dout) {
  __shared__ float rs[256], rq[256];
  const int b = blockIdx.x, t = threadIdx.x;
  rs[t] = mask[b * LL + t] + mask[b * LL + 256 + t];
  __syncthreads();
  for (int off = 128; off; off >>= 1) {
    if (t < off) rs[t] += rs[t + off];
    __syncthreads();
  }
  int idx = (int)(rs[0] + 0.5f) - 1;
  if (idx < 0) idx = 0;
  __syncthreads();

  const float* row = out + ((size_t)b * LL + idx) * DM;
  float x0 = row[t], x1 = row[t + 256], x2 = row[t + 512];
  rs[t] = x0 + x1 + x2;
  rq[t] = x0 * x0 + x1 * x1 + x2 * x2;
  __syncthreads();
  for (int off = 128; off; off >>= 1) {
    if (t < off) { rs[t] += rs[t + off]; rq[t] += rq[t + off]; }
    __syncthreads();
  }
  float mean = rs[0] * (1.f / 768.f);
  float var = rq[0] * (1.f / 768.f) - mean * mean;
  float inv = rsqrtf(var + 1e-5f);
  float y0 = (x0 - mean) * inv, y1 = (x1 - mean) * inv, y2 = (x2 - mean) * inv;
  dout[16 + b * DM + t] = y0;
  dout[16 + b * DM + 256 + t] = y1;
  dout[16 + b * DM + 512 + t] = y2;
  __syncthreads();
  rs[t] = y0 * Wh[t] + y1 * Wh[t + 256] + y2 * Wh[t + 512];
  __syncthreads();
  for (int off = 128; off; off >>= 1) {
    if (t < off) rs[t] += rs[t + off];
    __syncthreads();
  }
  if (t == 0) dout[b] = rs[0] + bh[0];
}

// ---------------------------------------------------------------------------
extern "C" void kernel_launch(void* const* d_in, const int* in_sizes, int n_in,
                              void* d_out, int out_size, void* d_ws, size_t ws_size,
                              hipStream_t stream) {
  const float* ccd    = (const float*)d_in[0];
  const float* mask   = (const float*)d_in[1];
  const float* dkpE   = (const float*)d_in[2];
  const int*   cmask  = (const int*)d_in[3];
  const float* W_gate = (const float*)d_in[4];
  const float* We1 = (const float*)d_in[5];
  const float* be1 = (const float*)d_in[6];
  const float* Weg = (const float*)d_in[7];
  const float* beg = (const float*)d_in[8];
  const float* We2 = (const float*)d_in[9];
  const float* be2 = (const float*)d_in[10];
  const float* Wm1 = (const float*)d_in[11];
  const float* bm1 = (const float*)d_in[12];
  const float* Wmg = (const float*)d_in[13];
  const float* bmg = (const float*)d_in[14];
  const float* Wm2 = (const float*)d_in[15];
  const float* bm2 = (const float*)d_in[16];
  const float* Wq = (const float*)d_in[17];
  const float* Wk = (const float*)d_in[18];
  const float* Wv = (const float*)d_in[19];
  const float* Wo = (const float*)d_in[20];
  const float* bq = (const float*)d_in[21];
  const float* bk = (const float*)d_in[22];
  const float* bv = (const float*)d_in[23];
  const float* bo = (const float*)d_in[24];
  const float* Wf1 = (const float*)d_in[25];
  const float* bf1 = (const float*)d_in[26];
  const float* Wfg = (const float*)d_in[27];
  const float* bfg = (const float*)d_in[28];
  const float* Wf2 = (const float*)d_in[29];
  const float* bf2 = (const float*)d_in[30];
  const float* W_head = (const float*)d_in[31];
  const float* b_head = (const float*)d_in[32];

  // ---- workspace layout (~170 MiB)
  char* base = (char*)d_ws;
  size_t used = 0;
  auto alloc = [&](size_t bytes) -> char* {
    char* r = base + used;
    used += (bytes + 255) & ~(size_t)255;
    return r;
  };
  float* dkp   = (float*)alloc((size_t)8192 * 4);
  float* gates = (float*)alloc((size_t)5 * 16 * DFF * 4);
  float* qkvb  = (float*)alloc((size_t)2 * QS * 4);
  float* out   = (float*)alloc((size_t)8192 * DM * 4);
  unsigned short* ubuf = (unsigned short*)alloc((size_t)8192 * DFF * 2);
  unsigned short* AspH = (unsigned short*)alloc((size_t)8192 * 960 * 2);
  const size_t szWe1 = (size_t)3072 * 960;
  const size_t szKN  = (size_t)3072 * 768;
  const size_t szAtt = (size_t)768 * 768;
  const size_t szQKV = (size_t)QS * 768;         // per-layer fused qkv planes
  unsigned short* We1tH = (unsigned short*)alloc(szWe1 * 2);
  unsigned short* We1tL = (unsigned short*)alloc(szWe1 * 2);
  unsigned short* We2tH = (unsigned short*)alloc(szKN * 2);
  unsigned short* We2tL = (unsigned short*)alloc(szKN * 2);
  unsigned short* Wm1tH = (unsigned short*)alloc(2 * szKN * 2);
  unsigned short* Wm1tL = (unsigned short*)alloc(2 * szKN * 2);
  unsigned short* Wm2tH = (unsigned short*)alloc(2 * szKN * 2);
  unsigned short* Wm2tL = (unsigned short*)alloc(2 * szKN * 2);
  unsigned short* WqkvH = (unsigned short*)alloc(2 * szQKV * 2);
  unsigned short* WqkvL = (unsigned short*)alloc(2 * szQKV * 2);
  unsigned short* WotH = (unsigned short*)alloc(2 * szAtt * 2);
  unsigned short* WotL = (unsigned short*)alloc(2 * szAtt * 2);
  unsigned short* Wf1tH = (unsigned short*)alloc(2 * szKN * 2);
  unsigned short* Wf1tL = (unsigned short*)alloc(2 * szKN * 2);
  unsigned short* Wf2tH = (unsigned short*)alloc(2 * szKN * 2);
  unsigned short* Wf2tL = (unsigned short*)alloc(2 * szKN * 2);
  if (used > ws_size) return;  // diagnostic: ws too small => output unwritten

  dim3 blk(256);

  // ---- weight prep (transpose + hi/lo fp16 split)
  wprep_kernel<<<dim3(30, 96, 1), blk, 0, stream>>>(We1, We1tH, We1tL, 900, 3072, 960);
  wprep_kernel<<<dim3(96, 24, 1), blk, 0, stream>>>(We2, We2tH, We2tL, 3072, 768, 3072);
  wprep_kernel<<<dim3(24, 96, 2), blk, 0, stream>>>(Wm1, Wm1tH, Wm1tL, 768, 3072, 768);
  wprep_kernel<<<dim3(96, 24, 2), blk, 0, stream>>>(Wm2, Wm2tH, Wm2tL, 3072, 768, 3072);
  for (int i = 0; i < 2; ++i) {   // fused qkv weight planes: rows q|k|v per layer
    wprep_kernel<<<dim3(24, 24, 1), blk, 0, stream>>>(
        Wq + (size_t)i * szAtt, WqkvH + (size_t)i * szQKV, WqkvL + (size_t)i * szQKV, 768, 768, 768);
    wprep_kernel<<<dim3(24, 24, 1), blk, 0, stream>>>(
        Wk + (size_t)i * szAtt, WqkvH + (size_t)i * szQKV + (size_t)768 * 768,
        WqkvL + (size_t)i * szQKV + (size_t)768 * 768, 768, 768, 768);
    wprep_kernel<<<dim3(24, 24, 1), blk, 0, stream>>>(
        Wv + (size_t)i * szAtt, WqkvH + (size_t)i * szQKV + (size_t)1536 * 768,
        WqkvL + (size_t)i * szQKV + (size_t)1536 * 768, 768, 768, 768);
  }
  wprep_kernel<<<dim3(24, 24, 2), blk, 0, stream>>>(Wo, WotH, WotL, 768, 768, 768);
  wprep_kernel<<<dim3(24, 96, 2), blk, 0, stream>>>(Wf1, Wf1tH, Wf1tL, 768, 3072, 768);
  wprep_kernel<<<dim3(96, 24, 2), blk, 0, stream>>>(Wf2, Wf2tH, Wf2tL, 3072, 768, 3072);

  asplit_kernel<<<30720, blk, 0, stream>>>(ccd, mask, AspH);
  packb_kernel<<<18, blk, 0, stream>>>(bq, bk, bv, qkvb);

  // gates
  dkp_kernel<<<32, blk, 0, stream>>>(dkpE, W_gate, dkp);
  const float* Wgs[5] = {Weg, Wmg, Wmg + (size_t)GDFF * DFF, Wfg, Wfg + (size_t)GDFF * DFF};
  const float* bgs[5] = {beg, bmg, bmg + DFF, bfg, bfg + DFF};
  for (int g = 0; g < 5; ++g)
    gate_kernel<<<192, blk, 0, stream>>>(dkp, Wgs[g], bgs[g], cmask, gates + (size_t)g * 16 * DFF);

  // patch embed gated FFN
  mgemm_kernel<1, 4, unsigned short><<<dim3(24, 64), blk, 0, stream>>>(
      AspH, We1tH, We1tL, be1, gates, nullptr, ubuf, DFF, 960);
  mgemm_kernel<0, 2, float><<<dim3(6, 128), blk, 0, stream>>>(
      ubuf, We2tH, We2tL, be2, nullptr, nullptr, out, DM, DFF);

  // intra MLP blocks: out += gated_ffn(ln(out))
  for (int i = 0; i < 2; ++i) {
    ln_kernel<<<8192, blk, 0, stream>>>(out, nullptr, AspH);
    mgemm_kernel<1, 4, unsigned short><<<dim3(24, 64), blk, 0, stream>>>(
        AspH, Wm1tH + (size_t)i * szKN, Wm1tL + (size_t)i * szKN,
        bm1 + i * DFF, gates + (size_t)(1 + i) * 16 * DFF, nullptr, ubuf, DFF, DM);
    mgemm_kernel<2, 2, float><<<dim3(6, 128), blk, 0, stream>>>(
        ubuf, Wm2tH + (size_t)i * szKN, Wm2tL + (size_t)i * szKN,
        bm2 + i * DM, nullptr, out, out, DM, DFF);
  }

  pe_kernel<<<24576, blk, 0, stream>>>(out, AspH);

  // encoder layers
  for (int i = 0; i < 2; ++i) {
    // fused QKV: [8192][2304] = A @ [Wq|Wk|Wv]^T
    mgemm_kernel<0, 4, unsigned short><<<dim3(18, 64), blk, 0, stream>>>(
        AspH, WqkvH + (size_t)i * szQKV, WqkvL + (size_t)i * szQKV,
        qkvb + (size_t)i * QS, nullptr, nullptr, ubuf, QS, DM);
    flash_kernel<<<dim3(8, 12, 16), blk, 0, stream>>>(ubuf, mask, AspH);
    mgemm_kernel<2, 2, float><<<dim3(6, 128), blk, 0, stream>>>(
        AspH, WotH + (size_t)i * szAtt, WotL + (size_t)i * szAtt,
        bo + i * DM, nullptr, out, out, DM, DM);
    ln_kernel<<<8192, blk, 0, stream>>>(out, out, AspH);
    mgemm_kernel<1, 4, unsigned short><<<dim3(24, 64), blk, 0, stream>>>(
        AspH, Wf1tH + (size_t)i * szKN, Wf1tL + (size_t)i * szKN,
        bf1 + i * DFF, gates + (size_t)(3 + i) * 16 * DFF, nullptr, ubuf, DFF, DM);
    mgemm_kernel<2, 2, float><<<dim3(6, 128), blk, 0, stream>>>(
        ubuf, Wf2tH + (size_t)i * szKN, Wf2tL + (size_t)i * szKN,
        bf2 + i * DM, nullptr, out, out, DM, DFF);
    ln_kernel<<<8192, blk, 0, stream>>>(out, out, AspH);
  }

  final_kernel<<<16, blk, 0, stream>>>(out, mask, W_head, b_head, (float*)d_out);
}